// Round 9
// baseline (479.592 us; speedup 1.0000x reference)
//
#include <hip/hip_runtime.h>
#include <hip/hip_fp16.h>
#include <math.h>

// Transformer-XL relative multi-head attention, MI355X. B=2,S=2048,D=512,H=8,dh=64.
// Round-9: r8 structure + register software-pipelining in attn_fused.
//   r8 diagnosis: VGPR=60 (squeezed by launch_bounds(256,4)) -> compiler issued
//   each L2/HBM load just-in-time -> ~2 loads in flight/CU -> 685 GB/s, all pipes
//   idle. Fix: explicit K-frag + pos prefetch registers, reloaded right after
//   consumption each k-tile (next tile's ~24 loads in flight across softmax+PV);
//   launch_bounds(256,3) so ~155 VGPR fits spill-free.
//  1. proj_kernel (fp32): QU(+u)/QV(+v) fp16 [s][d]; K fp16 [s][d]; VT fp16 [d][s];
//     Pb fp16 [s][d].
//  2. per head-chunk: pos_gemm (MFMA, pre-shifted scatter-store Psh, r3-validated
//     bijection) ; attn_fused (swapped-operand flash, split-K=4, barrier-free).
//  3. out_gemm (fp32): out = ctx @ Wo + bo.

#define S_LEN 2048
#define NH 8
#define DHD 64
#define DM 512
#define NBH 16
#define HEAD_ELEMS (S_LEN * DHD)
#define SS ((size_t)S_LEN * (size_t)S_LEN)

// workspace byte offsets
#define BY_QU  0u               // fp16 [16][2048][64]  4 MB
#define BY_QV  4194304u         // fp16 [16][2048][64]  4 MB
#define BY_K   8388608u         // fp16 [16][2048][64]  4 MB
#define BY_VT  12582912u        // fp16 [16][64][2048]  4 MB
#define BY_PB  16777216u        // fp16 [16][2048][64]  4 MB
#define BY_CTX 20971520u        // fp32 [2][2048][512]  8 MB
#define BY_PSH 29360128u        // fp16 [c][2048][2048] 8.39 MB/head (shifted pos)
#define PSH_HEAD_BYTES 8388608u

typedef short v8s __attribute__((ext_vector_type(8)));
typedef float v4f __attribute__((ext_vector_type(4)));

static __device__ __forceinline__ unsigned short f2h(float f) {
    __half h = __float2half(f);
    return *reinterpret_cast<unsigned short*>(&h);
}
static __device__ __forceinline__ float h2f(unsigned short u) {
    __half h = *reinterpret_cast<__half*>(&u);
    return __half2float(h);
}

// ---------------------------------------------------------------------------
// Projections (fp32 compute): C[4096,512] = A @ W (+bias), mode via blockIdx.z.
// ---------------------------------------------------------------------------
__global__ __launch_bounds__(256)
void proj_kernel(const float* __restrict__ x, const float* __restrict__ pos,
                 const float* __restrict__ Wq, const float* __restrict__ bq,
                 const float* __restrict__ Wk, const float* __restrict__ bk,
                 const float* __restrict__ Wv, const float* __restrict__ bvp,
                 const float* __restrict__ Wp,
                 const float* __restrict__ uvec, const float* __restrict__ vvec,
                 char* __restrict__ wsb)
{
    __shared__ float Ast[32][132];
    __shared__ float Bs[32][132];
    const int t = threadIdx.x;
    const int tx = t & 15, ty = t >> 4;
    const int mode = blockIdx.z;
    const int n0 = blockIdx.x * 128, m0 = blockIdx.y * 128;

    const float* A = (mode == 3) ? pos : x;
    const float* W = (mode == 0) ? Wq : (mode == 1) ? Wk : (mode == 2) ? Wv : Wp;

    float acc[8][8];
#pragma unroll
    for (int i = 0; i < 8; ++i)
#pragma unroll
        for (int j = 0; j < 8; ++j) acc[i][j] = 0.f;

    for (int k0 = 0; k0 < 512; k0 += 32) {
#pragma unroll
        for (int i = 0; i < 4; ++i) {
            int f = t + i * 256;
            int row = f >> 3, kq = f & 7;
            float4 a4 = *(const float4*)(A + (size_t)(m0 + row) * 512 + k0 + kq * 4);
            Ast[kq * 4 + 0][row] = a4.x; Ast[kq * 4 + 1][row] = a4.y;
            Ast[kq * 4 + 2][row] = a4.z; Ast[kq * 4 + 3][row] = a4.w;
        }
#pragma unroll
        for (int i = 0; i < 4; ++i) {
            int f = t + i * 256;
            int row = f >> 5, c4 = f & 31;
            *(float4*)&Bs[row][c4 * 4] =
                *(const float4*)(W + (size_t)(k0 + row) * 512 + n0 + c4 * 4);
        }
        __syncthreads();
#pragma unroll
        for (int kc = 0; kc < 32; ++kc) {
            float a[8], b[8];
            *(float4*)&a[0] = *(const float4*)&Ast[kc][ty * 8];
            *(float4*)&a[4] = *(const float4*)&Ast[kc][ty * 8 + 4];
            *(float4*)&b[0] = *(const float4*)&Bs[kc][tx * 8];
            *(float4*)&b[4] = *(const float4*)&Bs[kc][tx * 8 + 4];
#pragma unroll
            for (int i = 0; i < 8; ++i)
#pragma unroll
                for (int j = 0; j < 8; ++j) acc[i][j] = fmaf(a[i], b[j], acc[i][j]);
        }
        __syncthreads();
    }

    const int bb = m0 >> 11;

    if (mode == 0) {
        unsigned short* qu = (unsigned short*)(wsb + BY_QU);
        unsigned short* qv = (unsigned short*)(wsb + BY_QV);
#pragma unroll
        for (int i = 0; i < 8; ++i) {
            int gm = m0 + ty * 8 + i, srow = gm & 2047;
#pragma unroll
            for (int j4 = 0; j4 < 2; ++j4) {
                int gn = n0 + tx * 8 + j4 * 4;
                int h = gn >> 6, d = gn & 63;
                float4 bi = *(const float4*)(bq + gn);
                float4 uu = *(const float4*)(uvec + gn);
                float4 vv = *(const float4*)(vvec + gn);
                float c0 = acc[i][j4 * 4 + 0] + bi.x, c1 = acc[i][j4 * 4 + 1] + bi.y;
                float c2 = acc[i][j4 * 4 + 2] + bi.z, c3 = acc[i][j4 * 4 + 3] + bi.w;
                size_t o = ((size_t)(bb * NH + h) * S_LEN + srow) * DHD + d;
                ushort4 pu, pv2;
                pu.x = f2h(c0 + uu.x); pu.y = f2h(c1 + uu.y);
                pu.z = f2h(c2 + uu.z); pu.w = f2h(c3 + uu.w);
                pv2.x = f2h(c0 + vv.x); pv2.y = f2h(c1 + vv.y);
                pv2.z = f2h(c2 + vv.z); pv2.w = f2h(c3 + vv.w);
                *(ushort4*)(qu + o) = pu;
                *(ushort4*)(qv + o) = pv2;
            }
        }
    } else if (mode == 1 || mode == 3) {   // K / Pb fp16 [bh][s][d]
        unsigned short* dst = (unsigned short*)(wsb + (mode == 1 ? BY_K : BY_PB));
        const float* bias = (mode == 1) ? bk : nullptr;
#pragma unroll
        for (int i = 0; i < 8; ++i) {
            int gm = m0 + ty * 8 + i, srow = gm & 2047;
#pragma unroll
            for (int j4 = 0; j4 < 2; ++j4) {
                int gn = n0 + tx * 8 + j4 * 4;
                int h = gn >> 6, d = gn & 63;
                float4 bi = bias ? *(const float4*)(bias + gn)
                                 : make_float4(0.f, 0.f, 0.f, 0.f);
                size_t o = ((size_t)(bb * NH + h) * S_LEN + srow) * DHD + d;
                ushort4 pk;
                pk.x = f2h(acc[i][j4 * 4 + 0] + bi.x);
                pk.y = f2h(acc[i][j4 * 4 + 1] + bi.y);
                pk.z = f2h(acc[i][j4 * 4 + 2] + bi.z);
                pk.w = f2h(acc[i][j4 * 4 + 3] + bi.w);
                *(ushort4*)(dst + o) = pk;
            }
        }
    } else {                               // VT fp16 [bh][d][s]
        unsigned short* vt = (unsigned short*)(wsb + BY_VT);
#pragma unroll
        for (int j = 0; j < 8; ++j) {
            int gn = n0 + tx * 8 + j;
            int h = gn >> 6, d = gn & 63;
            float bval = bvp[gn];
            size_t rowbase = ((size_t)(bb * NH + h) * DHD + d) * S_LEN;
#pragma unroll
            for (int i4 = 0; i4 < 2; ++i4) {
                int srow = (m0 & 2047) + ty * 8 + i4 * 4;
                ushort4 pk;
                pk.x = f2h(acc[i4 * 4 + 0][j] + bval);
                pk.y = f2h(acc[i4 * 4 + 1][j] + bval);
                pk.z = f2h(acc[i4 * 4 + 2][j] + bval);
                pk.w = f2h(acc[i4 * 4 + 3][j] + bval);
                *(ushort4*)(vt + rowbase + srow) = pk;
            }
        }
    }
}

// ---------------------------------------------------------------------------
// pos GEMM via fp16 MFMA, no LDS: raw = QV_h[2048,64] @ Pb_h[2048,64]^T, but
// scatter-stored pre-shifted: raw[q][j] -> Psh[q][j+q-2047] if j >= 2047-q,
// else Psh[q-1][j+q+1] (q>0).  Bijection onto all (q,k) except k==q+1.
// ---------------------------------------------------------------------------
__global__ __launch_bounds__(256)
void pos_gemm(const unsigned short* __restrict__ qv,
              const unsigned short* __restrict__ pb,
              unsigned short* __restrict__ psh, int head_base)
{
    const int t = threadIdx.x;
    const int wave = t >> 6, lane = t & 63;
    const int quad = lane >> 4, l16 = lane & 15;
    const int wm = wave >> 1, wn = wave & 1;
    const int z = blockIdx.z, g = head_base + z;
    const int m0 = blockIdx.y * 128 + wm * 64;
    const int n0 = blockIdx.x * 128 + wn * 64;

    const unsigned short* A = qv + (size_t)g * HEAD_ELEMS;   // [s][d]
    const unsigned short* B = pb + (size_t)g * HEAD_ELEMS;   // [s][d]
    unsigned short* out = psh + (size_t)z * SS;

    v8s af[4][2], bf[4][2];
#pragma unroll
    for (int i = 0; i < 4; ++i)
#pragma unroll
        for (int kk = 0; kk < 2; ++kk) {
            af[i][kk] = *(const v8s*)(A + (size_t)(m0 + i * 16 + l16) * DHD + kk * 32 + quad * 8);
            bf[i][kk] = *(const v8s*)(B + (size_t)(n0 + i * 16 + l16) * DHD + kk * 32 + quad * 8);
        }

#pragma unroll
    for (int i = 0; i < 4; ++i)
#pragma unroll
        for (int j = 0; j < 4; ++j) {
            v4f c = (v4f){0.f, 0.f, 0.f, 0.f};
            c = __builtin_amdgcn_mfma_f32_16x16x32_f16(af[i][0], bf[j][0], c, 0, 0, 0);
            c = __builtin_amdgcn_mfma_f32_16x16x32_f16(af[i][1], bf[j][1], c, 0, 0, 0);
#pragma unroll
            for (int reg = 0; reg < 4; ++reg) {
                int qrow = m0 + i * 16 + quad * 4 + reg;
                int jcol = n0 + j * 16 + l16;
                unsigned short val = f2h(c[reg]);
                if (jcol >= 2047 - qrow) {
                    out[(size_t)qrow * S_LEN + (jcol + qrow - 2047)] = val;
                } else if (qrow > 0) {
                    out[(size_t)(qrow - 1) * S_LEN + (jcol + qrow + 1)] = val;
                }
            }
        }
}

// ---------------------------------------------------------------------------
// Flash attention, swapped operands, split-K=4, barrier-free k-loop, with
// register software-pipelining (K-frags + pos prefetched one tile ahead).
// Block 256 = 4 waves; all share q-tile [qt*16, +16); wave w owns keys
// [w*512, +512), 4 k-tiles of 128.
// QK^T: A=K-rows, B=Q-rows -> C[key=quad*4+reg + nt*16][q=l16].
// Pos: Psh[q][k] pre-shifted -> aligned ushort4 loads; k==q+1 zeroed (garbage).
// P: 8 x ds_write_b64 into Sp[q=l16][key], read back as A-frag v8s.
// PV: A=P, B=V(VT rows) -> accv rows q=quad*4+reg, col d=ntd*16+l16.
// End: one barrier; wave0 4-way flash-merges and stores ctx.
// launch_bounds(256,3): VGPR cap 170 so the ~155-reg pipelined set fits w/o spill.
// ---------------------------------------------------------------------------
__global__ __launch_bounds__(256, 3)
void attn_fused(const unsigned short* __restrict__ qu,
                const unsigned short* __restrict__ kdat,
                const unsigned short* __restrict__ vtg,
                const unsigned short* __restrict__ psh,
                float* __restrict__ ctx, int head_base)
{
    __shared__ unsigned short SpAll[4][2304];   // per-wave: P 16x136 / acc dump
    __shared__ float MlAll[4][128];             // per-wave: (m,l) per lane

    const int t = threadIdx.x;
    const int wave = t >> 6, lane = t & 63;
    const int quad = lane >> 4, l16 = lane & 15;
    const int z = blockIdx.x >> 7, qt = blockIdx.x & 127;
    const int g = head_base + z;
    const int q0 = qt * 16;
    const int q = q0 + l16;                     // this lane's softmax row

    const unsigned short* QU = qu   + (size_t)g * HEAD_ELEMS;   // [s][d]
    const unsigned short* Kg = kdat + (size_t)g * HEAD_ELEMS;   // [s][d]
    const unsigned short* Vg = vtg  + (size_t)g * HEAD_ELEMS;   // [d][s]
    const unsigned short* Ps = psh  + (size_t)z * SS;           // fp16 shifted
    unsigned short* Sp = &SpAll[wave][0];

    // loop-invariant Q fragments (B-operand)
    const v8s bq0 = *(const v8s*)(QU + (size_t)(q0 + l16) * DHD + quad * 8);
    const v8s bq1 = *(const v8s*)(QU + (size_t)(q0 + l16) * DHD + 32 + quad * 8);

    float m_run = -1e30f, l_run = 0.f;
    v4f accv[4];
#pragma unroll
    for (int r = 0; r < 4; ++r) accv[r] = (v4f){0.f, 0.f, 0.f, 0.f};
    const float scale = 0.04419417382415922f;   // 1/sqrt(512)
    const size_t prow = (size_t)q * S_LEN;

    // ---- prefetch tile 0 (K frags + pos quads) ----
    v8s kf0[8], kf1[8];
    ushort4 pl[8];
    {
        const int k0 = wave * 512;
#pragma unroll
        for (int nt = 0; nt < 8; ++nt) {
            kf0[nt] = *(const v8s*)(Kg + (size_t)(k0 + nt * 16 + l16) * DHD + quad * 8);
            kf1[nt] = *(const v8s*)(Kg + (size_t)(k0 + nt * 16 + l16) * DHD + 32 + quad * 8);
            pl[nt]  = *(const ushort4*)(Ps + prow + k0 + nt * 16 + quad * 4);
        }
    }

#pragma unroll
    for (int kt = 0; kt < 4; ++kt) {
        const int k0 = wave * 512 + kt * 128;

        // QK^T (consumes kf)
        v4f sacc[8];
#pragma unroll
        for (int nt = 0; nt < 8; ++nt) {
            v4f c = (v4f){0.f, 0.f, 0.f, 0.f};
            c = __builtin_amdgcn_mfma_f32_16x16x32_f16(kf0[nt], bq0, c, 0, 0, 0);
            c = __builtin_amdgcn_mfma_f32_16x16x32_f16(kf1[nt], bq1, c, 0, 0, 0);
            sacc[nt] = c;
        }

        // add pos (zero at k==q+1) and scale; local max (consumes pl)
        float tm = -1e30f;
#pragma unroll
        for (int nt = 0; nt < 8; ++nt) {
            int kb = k0 + nt * 16 + quad * 4;
            const unsigned short* pv4 = (const unsigned short*)&pl[nt];
#pragma unroll
            for (int reg = 0; reg < 4; ++reg) {
                float pv = ((kb + reg) == q + 1) ? 0.f : h2f(pv4[reg]);
                sacc[nt][reg] = (sacc[nt][reg] + pv) * scale;
                tm = fmaxf(tm, sacc[nt][reg]);
            }
        }

        // ---- prefetch next tile while softmax+PV run (kf/pl now dead) ----
        if (kt < 3) {
            const int k0n = k0 + 128;
#pragma unroll
            for (int nt = 0; nt < 8; ++nt) {
                kf0[nt] = *(const v8s*)(Kg + (size_t)(k0n + nt * 16 + l16) * DHD + quad * 8);
                kf1[nt] = *(const v8s*)(Kg + (size_t)(k0n + nt * 16 + l16) * DHD + 32 + quad * 8);
                pl[nt]  = *(const ushort4*)(Ps + prow + k0n + nt * 16 + quad * 4);
            }
        }

        // cross-quad max (cols of q=l16 live in all 4 quads)
        tm = fmaxf(tm, __shfl_xor(tm, 16));
        tm = fmaxf(tm, __shfl_xor(tm, 32));
        float mn = fmaxf(m_run, tm);
        float al = __expf(m_run - mn);
        float rs = 0.f;
#pragma unroll
        for (int nt = 0; nt < 8; ++nt)
#pragma unroll
            for (int reg = 0; reg < 4; ++reg) {
                sacc[nt][reg] = __expf(sacc[nt][reg] - mn);
                rs += sacc[nt][reg];
            }
        rs += __shfl_xor(rs, 16);
        rs += __shfl_xor(rs, 32);
        l_run = l_run * al + rs;
        m_run = mn;

        // rescale acc rows (row q' = q0+quad*4+reg needs alpha of that q')
        float alr[4];
#pragma unroll
        for (int reg = 0; reg < 4; ++reg) alr[reg] = __shfl(al, quad * 4 + reg);
#pragma unroll
        for (int ntd = 0; ntd < 4; ++ntd)
#pragma unroll
            for (int reg = 0; reg < 4; ++reg) accv[ntd][reg] *= alr[reg];

        // P -> Sp[q=l16][key] as 8B packs (wave-private, in-order)
#pragma unroll
        for (int nt = 0; nt < 8; ++nt) {
            ushort4 pk;
            pk.x = f2h(sacc[nt][0]); pk.y = f2h(sacc[nt][1]);
            pk.z = f2h(sacc[nt][2]); pk.w = f2h(sacc[nt][3]);
            *(ushort4*)&Sp[l16 * 136 + nt * 16 + quad * 4] = pk;
        }

        // PV: A=P, B=V
#pragma unroll
        for (int c4 = 0; c4 < 4; ++c4) {
            v8s ap = *(const v8s*)&Sp[l16 * 136 + c4 * 32 + quad * 8];
#pragma unroll
            for (int ntd = 0; ntd < 4; ++ntd) {
                v8s bv8 = *(const v8s*)(Vg + (size_t)(ntd * 16 + l16) * S_LEN +
                                        k0 + c4 * 32 + quad * 8);
                accv[ntd] = __builtin_amdgcn_mfma_f32_16x16x32_f16(ap, bv8, accv[ntd], 0, 0, 0);
            }
        }
    }

    // dump state; wave0 merges
    MlAll[wave][lane * 2]     = m_run;
    MlAll[wave][lane * 2 + 1] = l_run;
    if (wave != 0) {
        float* accSlot = (float*)&SpAll[wave][0];
#pragma unroll
        for (int ntd = 0; ntd < 4; ++ntd)
#pragma unroll
            for (int reg = 0; reg < 4; ++reg)
                accSlot[lane * 16 + ntd * 4 + reg] = accv[ntd][reg];
    }
    __syncthreads();
    if (wave == 0) {
        const int bb = g >> 3, h = g & 7;
        float ew[4][4], inv[4];
#pragma unroll
        for (int reg = 0; reg < 4; ++reg) {
            int qi = quad * 4 + reg;           // lane qi holds (m,l) for row q0+qi
            float mw[4], lw[4];
#pragma unroll
            for (int w = 0; w < 4; ++w) {
                mw[w] = MlAll[w][qi * 2];
                lw[w] = MlAll[w][qi * 2 + 1];
            }
            float ms = fmaxf(fmaxf(mw[0], mw[1]), fmaxf(mw[2], mw[3]));
            float lt = 0.f;
#pragma unroll
            for (int w = 0; w < 4; ++w) {
                ew[reg][w] = __expf(mw[w] - ms);
                lt += lw[w] * ew[reg][w];
            }
            inv[reg] = 1.f / lt;
        }
#pragma unroll
        for (int ntd = 0; ntd < 4; ++ntd) {
#pragma unroll
            for (int reg = 0; reg < 4; ++reg) {
                float o = accv[ntd][reg] * ew[reg][0];
#pragma unroll
                for (int w = 1; w < 4; ++w) {
                    const float* slot = (const float*)&SpAll[w][0];
                    o += slot[lane * 16 + ntd * 4 + reg] * ew[reg][w];
                }
                int qq = q0 + quad * 4 + reg;
                ctx[((size_t)(bb * S_LEN + qq)) * DM + h * DHD + ntd * 16 + l16] =
                    o * inv[reg];
            }
        }
    }
}

// ---------------------------------------------------------------------------
// Output GEMM: out[4096,512] = ctx @ Wo + bo (fp32)
// ---------------------------------------------------------------------------
__global__ __launch_bounds__(256)
void out_gemm(const float* __restrict__ ca,
              const float* __restrict__ Wo, const float* __restrict__ bo,
              float* __restrict__ out)
{
    __shared__ float Ast[32][132];
    __shared__ float Bs[32][132];
    const int t = threadIdx.x;
    const int tx = t & 15, ty = t >> 4;
    const int n0 = blockIdx.x * 128, m0 = blockIdx.y * 128;

    float acc[8][8];
#pragma unroll
    for (int i = 0; i < 8; ++i)
#pragma unroll
        for (int j = 0; j < 8; ++j) acc[i][j] = 0.f;

    for (int k0 = 0; k0 < 512; k0 += 32) {
#pragma unroll
        for (int i = 0; i < 4; ++i) {
            int f = t + i * 256;
            int row = f >> 3, kq = f & 7;
            float4 a4 = *(const float4*)(ca + (size_t)(m0 + row) * 512 + k0 + kq * 4);
            Ast[kq * 4 + 0][row] = a4.x; Ast[kq * 4 + 1][row] = a4.y;
            Ast[kq * 4 + 2][row] = a4.z; Ast[kq * 4 + 3][row] = a4.w;
        }
#pragma unroll
        for (int i = 0; i < 4; ++i) {
            int f = t + i * 256;
            int row = f >> 5, c4 = f & 31;
            *(float4*)&Bs[row][c4 * 4] =
                *(const float4*)(Wo + (size_t)(k0 + row) * 512 + n0 + c4 * 4);
        }
        __syncthreads();
#pragma unroll
        for (int kc = 0; kc < 32; ++kc) {
            float a[8], b[8];
            *(float4*)&a[0] = *(const float4*)&Ast[kc][ty * 8];
            *(float4*)&a[4] = *(const float4*)&Ast[kc][ty * 8 + 4];
            *(float4*)&b[0] = *(const float4*)&Bs[kc][tx * 8];
            *(float4*)&b[4] = *(const float4*)&Bs[kc][tx * 8 + 4];
#pragma unroll
            for (int i = 0; i < 8; ++i)
#pragma unroll
                for (int j = 0; j < 8; ++j) acc[i][j] = fmaf(a[i], b[j], acc[i][j]);
        }
        __syncthreads();
    }

#pragma unroll
    for (int i = 0; i < 8; ++i) {
        int gm = m0 + ty * 8 + i;
#pragma unroll
        for (int j4 = 0; j4 < 2; ++j4) {
            int gn = n0 + tx * 8 + j4 * 4;
            float4 bi = *(const float4*)(bo + gn);
            *(float4*)(out + (size_t)gm * 512 + gn) =
                make_float4(acc[i][j4 * 4 + 0] + bi.x, acc[i][j4 * 4 + 1] + bi.y,
                            acc[i][j4 * 4 + 2] + bi.z, acc[i][j4 * 4 + 3] + bi.w);
        }
    }
}

// Fallback when ws_size is insufficient: clean mismatch instead of OOB writes.
__global__ void zero_fill(float* __restrict__ p, int n)
{
    int i = blockIdx.x * 256 + threadIdx.x;
    if (i < n) p[i] = 0.f;
}

// ---------------------------------------------------------------------------
extern "C" void kernel_launch(void* const* d_in, const int* in_sizes, int n_in,
                              void* d_out, int out_size, void* d_ws, size_t ws_size,
                              hipStream_t stream)
{
    const float* x   = (const float*)d_in[0];
    const float* pos = (const float*)d_in[1];
    const float* Wq  = (const float*)d_in[2];
    const float* bq  = (const float*)d_in[3];
    const float* Wk  = (const float*)d_in[4];
    const float* bk  = (const float*)d_in[5];
    const float* Wv  = (const float*)d_in[6];
    const float* bv  = (const float*)d_in[7];
    const float* Wp  = (const float*)d_in[8];
    const float* u   = (const float*)d_in[9];
    const float* v   = (const float*)d_in[10];
    const float* Wo  = (const float*)d_in[11];
    const float* bo  = (const float*)d_in[12];
    char* wsb  = (char*)d_ws;
    float* out = (float*)d_out;

    // Workspace guard: need BY_PSH + >=1 head of shifted pos (37.7 MB min).
    if (ws_size < (size_t)BY_PSH + PSH_HEAD_BYTES) {
        zero_fill<<<(out_size + 255) / 256, 256, 0, stream>>>(out, out_size);
        return;
    }

    // 1. projections
    proj_kernel<<<dim3(4, 32, 4), 256, 0, stream>>>(x, pos, Wq, bq, Wk, bk, Wv, bv,
                                                    Wp, u, v, wsb);

    // 2. attention in head-chunks sized to workspace
    int c = (int)((ws_size - (size_t)BY_PSH) / (size_t)PSH_HEAD_BYTES);
    if (c < 1) c = 1;
    if (c > NBH) c = NBH;

    for (int g0 = 0; g0 < NBH; g0 += c) {
        int cc = (NBH - g0 < c) ? (NBH - g0) : c;
        pos_gemm<<<dim3(16, 16, cc), 256, 0, stream>>>(
            (const unsigned short*)(wsb + BY_QV),
            (const unsigned short*)(wsb + BY_PB),
            (unsigned short*)(wsb + BY_PSH), g0);
        attn_fused<<<dim3(cc * 128), 256, 0, stream>>>(
            (const unsigned short*)(wsb + BY_QU),
            (const unsigned short*)(wsb + BY_K),
            (const unsigned short*)(wsb + BY_VT),
            (const unsigned short*)(wsb + BY_PSH),
            (float*)(wsb + BY_CTX), g0);
    }

    // 3. output projection
    out_gemm<<<dim3(4, 32, 1), 256, 0, stream>>>((const float*)(wsb + BY_CTX),
                                                 Wo, bo, out);
}

// Round 10
// 361.341 us; speedup vs baseline: 1.3273x; 1.3273x over previous
//
#include <hip/hip_runtime.h>
#include <hip/hip_fp16.h>
#include <math.h>

// Transformer-XL relative multi-head attention, MI355X. B=2,S=2048,D=512,H=8,dh=64.
// Round-10: r8 attention (best measured: 162us) + ALL GEMMs moved to fp16 MFMA.
//   r9 post-mortem: register prefetch raised BW 685->1212 GB/s but cost occupancy
//   (44->30%) and scratch traffic; net neutral -> reverted.
//   This round attacks the ~315us OUTSIDE attn: fp32 proj (~110us) and out (~40us)
//   become fp16-MFMA kernels; tiny prep kernels convert x/pos to fp16 and the five
//   weight matrices to fp16 TRANSPOSED (W^T[n][k]) so every MFMA fragment is a
//   contiguous 16B load. Operand order per mode picks the C-layout that makes all
//   epilogue stores aligned ushort4/float4.
//  1. conv_inputs : x,pos fp32 -> xh,ph fp16.
//  2. conv_wt     : Wq,Wk,Wv,Wp,Wo -> WT fp16 [n][k] (LDS 64x64 transpose).
//  3. proj_mfma   : QU(+u)/QV(+v), K (swapped: C[d][s]); VT (C[s][d]); Pb.
//  4. per head-chunk: pos_gemm (pre-shifted Psh scatter, r8) ;
//     attn_fused (r8 exact: swapped operands, split-K=4, barrier-free; ctx fp16).
//  5. out_mfma    : out(fp32) = ctx(fp16) @ Wo + bo, swapped -> float4 stores.

#define S_LEN 2048
#define NH 8
#define DHD 64
#define DM 512
#define NBH 16
#define HEAD_ELEMS (S_LEN * DHD)
#define SS ((size_t)S_LEN * (size_t)S_LEN)

// workspace byte offsets
#define BY_QU  0u               // fp16 [16][2048][64]  4 MB
#define BY_QV  4194304u         // fp16 [16][2048][64]  4 MB
#define BY_K   8388608u         // fp16 [16][2048][64]  4 MB
#define BY_VT  12582912u        // fp16 [16][64][2048]  4 MB
#define BY_PB  16777216u        // fp16 [16][2048][64]  4 MB
#define BY_XH  20971520u        // fp16 [2][2048][512]  4 MB
#define BY_PH  25165824u        // fp16 [2][2048][512]  4 MB
#define BY_WT  29360128u        // fp16 [5][512][512] transposed, 2.62 MB
#define BY_CTX 31981568u        // fp16 [2][2048][512]  4 MB
#define BY_PSH 36175872u        // fp16 [c][2048][2048] 8.39 MB/head (shifted pos)
#define PSH_HEAD_BYTES 8388608u
#define WT_MAT_HALFS 262144u

typedef short v8s __attribute__((ext_vector_type(8)));
typedef float v4f __attribute__((ext_vector_type(4)));

static __device__ __forceinline__ unsigned short f2h(float f) {
    __half h = __float2half(f);
    return *reinterpret_cast<unsigned short*>(&h);
}
static __device__ __forceinline__ float h2f(unsigned short u) {
    __half h = *reinterpret_cast<__half*>(&u);
    return __half2float(h);
}

// ---------------------------------------------------------------------------
// conv_inputs: fp32 -> fp16, 4 els/thread. z: 0 = x, 1 = pos.
// ---------------------------------------------------------------------------
__global__ __launch_bounds__(256)
void conv_inputs(const float* __restrict__ x, const float* __restrict__ pos,
                 char* __restrict__ wsb)
{
    const float* src = blockIdx.z ? pos : x;
    unsigned short* dst = (unsigned short*)(wsb + (blockIdx.z ? BY_PH : BY_XH));
    int i = (blockIdx.x * 256 + threadIdx.x) * 4;
    float4 a = *(const float4*)(src + i);
    ushort4 p;
    p.x = f2h(a.x); p.y = f2h(a.y); p.z = f2h(a.z); p.w = f2h(a.w);
    *(ushort4*)(dst + i) = p;
}

// ---------------------------------------------------------------------------
// conv_wt: WT[m][n][k] = W_m[k][n] fp16. 64x64 LDS tile transpose.
// grid (8,8,5): x = n-tile, y = k-tile, z = matrix (q,k,v,p,o).
// ---------------------------------------------------------------------------
__global__ __launch_bounds__(256)
void conv_wt(const float* __restrict__ Wq, const float* __restrict__ Wk,
             const float* __restrict__ Wv, const float* __restrict__ Wp,
             const float* __restrict__ Wo, char* __restrict__ wsb)
{
    __shared__ float T[64][65];
    const float* W = (blockIdx.z == 0) ? Wq : (blockIdx.z == 1) ? Wk :
                     (blockIdx.z == 2) ? Wv : (blockIdx.z == 3) ? Wp : Wo;
    unsigned short* WT = (unsigned short*)(wsb + BY_WT) + blockIdx.z * WT_MAT_HALFS;
    const int n0 = blockIdx.x * 64, k0 = blockIdx.y * 64;
    const int t = threadIdx.x;
#pragma unroll
    for (int i = 0; i < 4; ++i) {
        int f = t + i * 256;
        int row = f >> 4, c4 = f & 15;
        *(float4*)&T[row][c4 * 4] = *(const float4*)(W + (size_t)(k0 + row) * 512 + n0 + c4 * 4);
    }
    __syncthreads();
#pragma unroll
    for (int i = 0; i < 4; ++i) {
        int f = t + i * 256;
        int n = f >> 4, k4 = f & 15;
        ushort4 p;
        p.x = f2h(T[k4 * 4 + 0][n]); p.y = f2h(T[k4 * 4 + 1][n]);
        p.z = f2h(T[k4 * 4 + 2][n]); p.w = f2h(T[k4 * 4 + 3][n]);
        *(ushort4*)(WT + (size_t)(n0 + n) * 512 + k0 + k4 * 4) = p;
    }
}

// ---------------------------------------------------------------------------
// proj_mfma: all four projections via fp16 MFMA, no LDS, 4 waves = 2x2 64x64.
// grid (32, 4, 4): x = s-tile(128), y = d-tile(128), z = mode.
// modes 0(Q),1(K),3(P): SWAPPED  C[d][s]: A=WT rows d, B=xh/ph rows s.
//   lane holds 4 consecutive d (quad*4+reg) at fixed s -> [s][d] ushort4 store.
// mode 2(V): C[s][d]: A=xh rows s, B=WTv rows d.
//   lane holds 4 consecutive s at fixed d -> VT[d][s] ushort4 store.
// ---------------------------------------------------------------------------
__global__ __launch_bounds__(256)
void proj_mfma(const float* __restrict__ bq, const float* __restrict__ bk,
               const float* __restrict__ bvp,
               const float* __restrict__ uvec, const float* __restrict__ vvec,
               char* __restrict__ wsb)
{
    const int t = threadIdx.x;
    const int wave = t >> 6, lane = t & 63;
    const int quad = lane >> 4, l16 = lane & 15;
    const int wm = wave >> 1, wn = wave & 1;
    const int mode = blockIdx.z;
    const unsigned short* xh = (const unsigned short*)(wsb + BY_XH);
    const unsigned short* ph = (const unsigned short*)(wsb + BY_PH);
    const unsigned short* wt = (const unsigned short*)(wsb + BY_WT);

    v4f acc[4][4];
#pragma unroll
    for (int i = 0; i < 4; ++i)
#pragma unroll
        for (int j = 0; j < 4; ++j) acc[i][j] = (v4f){0.f, 0.f, 0.f, 0.f};

    if (mode != 2) {
        const int d0 = blockIdx.y * 128 + wm * 64;
        const int s0 = blockIdx.x * 128 + wn * 64;
        const int mat = (mode == 0) ? 0 : (mode == 1) ? 1 : 3;
        const unsigned short* A = wt + (size_t)mat * WT_MAT_HALFS;   // [d][k]
        const unsigned short* B = (mode == 3) ? ph : xh;             // [s][k]

        for (int kk = 0; kk < 16; ++kk) {
            v8s af[4], bf[4];
#pragma unroll
            for (int i = 0; i < 4; ++i) {
                af[i] = *(const v8s*)(A + (size_t)(d0 + i * 16 + l16) * 512 + kk * 32 + quad * 8);
                bf[i] = *(const v8s*)(B + (size_t)(s0 + i * 16 + l16) * 512 + kk * 32 + quad * 8);
            }
#pragma unroll
            for (int i = 0; i < 4; ++i)
#pragma unroll
                for (int j = 0; j < 4; ++j)
                    acc[i][j] = __builtin_amdgcn_mfma_f32_16x16x32_f16(af[i], bf[j], acc[i][j], 0, 0, 0);
        }

#pragma unroll
        for (int i = 0; i < 4; ++i) {
            int db = d0 + i * 16 + quad * 4;        // 4 consecutive d
            int h = db >> 6, dl = db & 63;
            float4 b4 = (mode == 3) ? make_float4(0.f, 0.f, 0.f, 0.f)
                        : (mode == 0) ? *(const float4*)(bq + db)
                                      : *(const float4*)(bk + db);
#pragma unroll
            for (int j = 0; j < 4; ++j) {
                int s = s0 + j * 16 + l16;
                int bb = s >> 11, srow = s & 2047;
                size_t o = ((size_t)(bb * NH + h) * S_LEN + srow) * DHD + dl;
                if (mode == 0) {
                    float4 u4 = *(const float4*)(uvec + db);
                    float4 v4 = *(const float4*)(vvec + db);
                    unsigned short* qu = (unsigned short*)(wsb + BY_QU);
                    unsigned short* qv = (unsigned short*)(wsb + BY_QV);
                    ushort4 pu, pv;
                    pu.x = f2h(acc[i][j][0] + b4.x + u4.x);
                    pu.y = f2h(acc[i][j][1] + b4.y + u4.y);
                    pu.z = f2h(acc[i][j][2] + b4.z + u4.z);
                    pu.w = f2h(acc[i][j][3] + b4.w + u4.w);
                    pv.x = f2h(acc[i][j][0] + b4.x + v4.x);
                    pv.y = f2h(acc[i][j][1] + b4.y + v4.y);
                    pv.z = f2h(acc[i][j][2] + b4.z + v4.z);
                    pv.w = f2h(acc[i][j][3] + b4.w + v4.w);
                    *(ushort4*)(qu + o) = pu;
                    *(ushort4*)(qv + o) = pv;
                } else {
                    unsigned short* dst = (unsigned short*)(wsb + (mode == 1 ? BY_K : BY_PB));
                    ushort4 pk;
                    pk.x = f2h(acc[i][j][0] + b4.x);
                    pk.y = f2h(acc[i][j][1] + b4.y);
                    pk.z = f2h(acc[i][j][2] + b4.z);
                    pk.w = f2h(acc[i][j][3] + b4.w);
                    *(ushort4*)(dst + o) = pk;
                }
            }
        }
    } else {
        const int s0 = blockIdx.x * 128 + wm * 64;
        const int d0 = blockIdx.y * 128 + wn * 64;
        const unsigned short* A = xh;                                 // [s][k]
        const unsigned short* B = wt + (size_t)2 * WT_MAT_HALFS;      // [d][k]

        for (int kk = 0; kk < 16; ++kk) {
            v8s af[4], bf[4];
#pragma unroll
            for (int i = 0; i < 4; ++i) {
                af[i] = *(const v8s*)(A + (size_t)(s0 + i * 16 + l16) * 512 + kk * 32 + quad * 8);
                bf[i] = *(const v8s*)(B + (size_t)(d0 + i * 16 + l16) * 512 + kk * 32 + quad * 8);
            }
#pragma unroll
            for (int i = 0; i < 4; ++i)
#pragma unroll
                for (int j = 0; j < 4; ++j)
                    acc[i][j] = __builtin_amdgcn_mfma_f32_16x16x32_f16(af[i], bf[j], acc[i][j], 0, 0, 0);
        }

        unsigned short* vt = (unsigned short*)(wsb + BY_VT);
#pragma unroll
        for (int j = 0; j < 4; ++j) {
            int d = d0 + j * 16 + l16;
            int h = d >> 6, dl = d & 63;
            float bval = bvp[d];
#pragma unroll
            for (int i = 0; i < 4; ++i) {
                int sb = s0 + i * 16 + quad * 4;    // 4 consecutive s
                int bb = sb >> 11, srow = sb & 2047;
                size_t o = ((size_t)(bb * NH + h) * DHD + dl) * S_LEN + srow;
                ushort4 pk;
                pk.x = f2h(acc[i][j][0] + bval);
                pk.y = f2h(acc[i][j][1] + bval);
                pk.z = f2h(acc[i][j][2] + bval);
                pk.w = f2h(acc[i][j][3] + bval);
                *(ushort4*)(vt + o) = pk;
            }
        }
    }
}

// ---------------------------------------------------------------------------
// pos GEMM (r8): raw = QV_h @ Pb_h^T, scatter-stored pre-shifted Psh.
// raw[q][j] -> Psh[q][j+q-2047] if j >= 2047-q, else Psh[q-1][j+q+1] (q>0).
// ---------------------------------------------------------------------------
__global__ __launch_bounds__(256)
void pos_gemm(const unsigned short* __restrict__ qv,
              const unsigned short* __restrict__ pb,
              unsigned short* __restrict__ psh, int head_base)
{
    const int t = threadIdx.x;
    const int wave = t >> 6, lane = t & 63;
    const int quad = lane >> 4, l16 = lane & 15;
    const int wm = wave >> 1, wn = wave & 1;
    const int z = blockIdx.z, g = head_base + z;
    const int m0 = blockIdx.y * 128 + wm * 64;
    const int n0 = blockIdx.x * 128 + wn * 64;

    const unsigned short* A = qv + (size_t)g * HEAD_ELEMS;   // [s][d]
    const unsigned short* B = pb + (size_t)g * HEAD_ELEMS;   // [s][d]
    unsigned short* out = psh + (size_t)z * SS;

    v8s af[4][2], bf[4][2];
#pragma unroll
    for (int i = 0; i < 4; ++i)
#pragma unroll
        for (int kk = 0; kk < 2; ++kk) {
            af[i][kk] = *(const v8s*)(A + (size_t)(m0 + i * 16 + l16) * DHD + kk * 32 + quad * 8);
            bf[i][kk] = *(const v8s*)(B + (size_t)(n0 + i * 16 + l16) * DHD + kk * 32 + quad * 8);
        }

#pragma unroll
    for (int i = 0; i < 4; ++i)
#pragma unroll
        for (int j = 0; j < 4; ++j) {
            v4f c = (v4f){0.f, 0.f, 0.f, 0.f};
            c = __builtin_amdgcn_mfma_f32_16x16x32_f16(af[i][0], bf[j][0], c, 0, 0, 0);
            c = __builtin_amdgcn_mfma_f32_16x16x32_f16(af[i][1], bf[j][1], c, 0, 0, 0);
#pragma unroll
            for (int reg = 0; reg < 4; ++reg) {
                int qrow = m0 + i * 16 + quad * 4 + reg;
                int jcol = n0 + j * 16 + l16;
                unsigned short val = f2h(c[reg]);
                if (jcol >= 2047 - qrow) {
                    out[(size_t)qrow * S_LEN + (jcol + qrow - 2047)] = val;
                } else if (qrow > 0) {
                    out[(size_t)(qrow - 1) * S_LEN + (jcol + qrow + 1)] = val;
                }
            }
        }
}

// ---------------------------------------------------------------------------
// Flash attention (r8 exact config; ctx stored fp16).
// Block 256 = 4 waves; q-tile [qt*16,+16); wave w owns keys [w*512,+512).
// ---------------------------------------------------------------------------
__global__ __launch_bounds__(256, 4)
void attn_fused(const unsigned short* __restrict__ qu,
                const unsigned short* __restrict__ kdat,
                const unsigned short* __restrict__ vtg,
                const unsigned short* __restrict__ psh,
                unsigned short* __restrict__ ctx, int head_base)
{
    __shared__ unsigned short SpAll[4][2304];
    __shared__ float MlAll[4][128];

    const int t = threadIdx.x;
    const int wave = t >> 6, lane = t & 63;
    const int quad = lane >> 4, l16 = lane & 15;
    const int z = blockIdx.x >> 7, qt = blockIdx.x & 127;
    const int g = head_base + z;
    const int q0 = qt * 16;
    const int q = q0 + l16;

    const unsigned short* QU = qu   + (size_t)g * HEAD_ELEMS;
    const unsigned short* Kg = kdat + (size_t)g * HEAD_ELEMS;
    const unsigned short* Vg = vtg  + (size_t)g * HEAD_ELEMS;
    const unsigned short* Ps = psh  + (size_t)z * SS;
    unsigned short* Sp = &SpAll[wave][0];

    const v8s bq0 = *(const v8s*)(QU + (size_t)(q0 + l16) * DHD + quad * 8);
    const v8s bq1 = *(const v8s*)(QU + (size_t)(q0 + l16) * DHD + 32 + quad * 8);

    float m_run = -1e30f, l_run = 0.f;
    v4f accv[4];
#pragma unroll
    for (int r = 0; r < 4; ++r) accv[r] = (v4f){0.f, 0.f, 0.f, 0.f};
    const float scale = 0.04419417382415922f;
    const size_t prow = (size_t)q * S_LEN;

    for (int kt = 0; kt < 4; ++kt) {
        const int k0 = wave * 512 + kt * 128;

        ushort4 pl[8];
#pragma unroll
        for (int nt = 0; nt < 8; ++nt)
            pl[nt] = *(const ushort4*)(Ps + prow + k0 + nt * 16 + quad * 4);

        v4f sacc[8];
#pragma unroll
        for (int nt = 0; nt < 8; ++nt) {
            v8s a0 = *(const v8s*)(Kg + (size_t)(k0 + nt * 16 + l16) * DHD + quad * 8);
            v8s a1 = *(const v8s*)(Kg + (size_t)(k0 + nt * 16 + l16) * DHD + 32 + quad * 8);
            v4f c = (v4f){0.f, 0.f, 0.f, 0.f};
            c = __builtin_amdgcn_mfma_f32_16x16x32_f16(a0, bq0, c, 0, 0, 0);
            c = __builtin_amdgcn_mfma_f32_16x16x32_f16(a1, bq1, c, 0, 0, 0);
            sacc[nt] = c;
        }

        float tm = -1e30f;
#pragma unroll
        for (int nt = 0; nt < 8; ++nt) {
            int kb = k0 + nt * 16 + quad * 4;
            const unsigned short* pv4 = (const unsigned short*)&pl[nt];
#pragma unroll
            for (int reg = 0; reg < 4; ++reg) {
                float pv = ((kb + reg) == q + 1) ? 0.f : h2f(pv4[reg]);
                sacc[nt][reg] = (sacc[nt][reg] + pv) * scale;
                tm = fmaxf(tm, sacc[nt][reg]);
            }
        }
        tm = fmaxf(tm, __shfl_xor(tm, 16));
        tm = fmaxf(tm, __shfl_xor(tm, 32));
        float mn = fmaxf(m_run, tm);
        float al = __expf(m_run - mn);
        float rs = 0.f;
#pragma unroll
        for (int nt = 0; nt < 8; ++nt)
#pragma unroll
            for (int reg = 0; reg < 4; ++reg) {
                sacc[nt][reg] = __expf(sacc[nt][reg] - mn);
                rs += sacc[nt][reg];
            }
        rs += __shfl_xor(rs, 16);
        rs += __shfl_xor(rs, 32);
        l_run = l_run * al + rs;
        m_run = mn;

        float alr[4];
#pragma unroll
        for (int reg = 0; reg < 4; ++reg) alr[reg] = __shfl(al, quad * 4 + reg);
#pragma unroll
        for (int ntd = 0; ntd < 4; ++ntd)
#pragma unroll
            for (int reg = 0; reg < 4; ++reg) accv[ntd][reg] *= alr[reg];

#pragma unroll
        for (int nt = 0; nt < 8; ++nt) {
            ushort4 pk;
            pk.x = f2h(sacc[nt][0]); pk.y = f2h(sacc[nt][1]);
            pk.z = f2h(sacc[nt][2]); pk.w = f2h(sacc[nt][3]);
            *(ushort4*)&Sp[l16 * 136 + nt * 16 + quad * 4] = pk;
        }

#pragma unroll
        for (int c4 = 0; c4 < 4; ++c4) {
            v8s ap = *(const v8s*)&Sp[l16 * 136 + c4 * 32 + quad * 8];
#pragma unroll
            for (int ntd = 0; ntd < 4; ++ntd) {
                v8s bv8 = *(const v8s*)(Vg + (size_t)(ntd * 16 + l16) * S_LEN +
                                        k0 + c4 * 32 + quad * 8);
                accv[ntd] = __builtin_amdgcn_mfma_f32_16x16x32_f16(ap, bv8, accv[ntd], 0, 0, 0);
            }
        }
    }

    MlAll[wave][lane * 2]     = m_run;
    MlAll[wave][lane * 2 + 1] = l_run;
    if (wave != 0) {
        float* accSlot = (float*)&SpAll[wave][0];
#pragma unroll
        for (int ntd = 0; ntd < 4; ++ntd)
#pragma unroll
            for (int reg = 0; reg < 4; ++reg)
                accSlot[lane * 16 + ntd * 4 + reg] = accv[ntd][reg];
    }
    __syncthreads();
    if (wave == 0) {
        const int bb = g >> 3, h = g & 7;
        float ew[4][4], inv[4];
#pragma unroll
        for (int reg = 0; reg < 4; ++reg) {
            int qi = quad * 4 + reg;
            float mw[4], lw[4];
#pragma unroll
            for (int w = 0; w < 4; ++w) {
                mw[w] = MlAll[w][qi * 2];
                lw[w] = MlAll[w][qi * 2 + 1];
            }
            float ms = fmaxf(fmaxf(mw[0], mw[1]), fmaxf(mw[2], mw[3]));
            float lt = 0.f;
#pragma unroll
            for (int w = 0; w < 4; ++w) {
                ew[reg][w] = __expf(mw[w] - ms);
                lt += lw[w] * ew[reg][w];
            }
            inv[reg] = 1.f / lt;
        }
#pragma unroll
        for (int ntd = 0; ntd < 4; ++ntd) {
#pragma unroll
            for (int reg = 0; reg < 4; ++reg) {
                float o = accv[ntd][reg] * ew[reg][0];
#pragma unroll
                for (int w = 1; w < 4; ++w) {
                    const float* slot = (const float*)&SpAll[w][0];
                    o += slot[lane * 16 + ntd * 4 + reg] * ew[reg][w];
                }
                int qq = q0 + quad * 4 + reg;
                ctx[((size_t)(bb * S_LEN + qq)) * DM + h * DHD + ntd * 16 + l16] =
                    f2h(o * inv[reg]);
            }
        }
    }
}

// ---------------------------------------------------------------------------
// out_mfma: out(fp32)[s][n] = ctx(fp16) @ Wo + bo.  SWAPPED: C[n][s],
// A = WoT rows n, B = ctxh rows s -> lane holds 4 consecutive n at fixed s
// -> float4 stores of d_out.  grid (32, 4): x = s-tile(128), y = n-tile(128).
// ---------------------------------------------------------------------------
__global__ __launch_bounds__(256)
void out_mfma(const float* __restrict__ bo, const char* __restrict__ wsb,
              float* __restrict__ out)
{
    const int t = threadIdx.x;
    const int wave = t >> 6, lane = t & 63;
    const int quad = lane >> 4, l16 = lane & 15;
    const int wm = wave >> 1, wn = wave & 1;
    const int n0 = blockIdx.y * 128 + wm * 64;
    const int s0 = blockIdx.x * 128 + wn * 64;
    const unsigned short* A = (const unsigned short*)(wsb + BY_WT) + (size_t)4 * WT_MAT_HALFS;
    const unsigned short* B = (const unsigned short*)(wsb + BY_CTX);

    v4f acc[4][4];
#pragma unroll
    for (int i = 0; i < 4; ++i)
#pragma unroll
        for (int j = 0; j < 4; ++j) acc[i][j] = (v4f){0.f, 0.f, 0.f, 0.f};

    for (int kk = 0; kk < 16; ++kk) {
        v8s af[4], bf[4];
#pragma unroll
        for (int i = 0; i < 4; ++i) {
            af[i] = *(const v8s*)(A + (size_t)(n0 + i * 16 + l16) * 512 + kk * 32 + quad * 8);
            bf[i] = *(const v8s*)(B + (size_t)(s0 + i * 16 + l16) * 512 + kk * 32 + quad * 8);
        }
#pragma unroll
        for (int i = 0; i < 4; ++i)
#pragma unroll
            for (int j = 0; j < 4; ++j)
                acc[i][j] = __builtin_amdgcn_mfma_f32_16x16x32_f16(af[i], bf[j], acc[i][j], 0, 0, 0);
    }

#pragma unroll
    for (int i = 0; i < 4; ++i) {
        int nb = n0 + i * 16 + quad * 4;
        float4 b4 = *(const float4*)(bo + nb);
#pragma unroll
        for (int j = 0; j < 4; ++j) {
            int s = s0 + j * 16 + l16;
            *(float4*)(out + (size_t)s * DM + nb) =
                make_float4(acc[i][j][0] + b4.x, acc[i][j][1] + b4.y,
                            acc[i][j][2] + b4.z, acc[i][j][3] + b4.w);
        }
    }
}

// Fallback when ws_size is insufficient: clean mismatch instead of OOB writes.
__global__ void zero_fill(float* __restrict__ p, int n)
{
    int i = blockIdx.x * 256 + threadIdx.x;
    if (i < n) p[i] = 0.f;
}

// ---------------------------------------------------------------------------
extern "C" void kernel_launch(void* const* d_in, const int* in_sizes, int n_in,
                              void* d_out, int out_size, void* d_ws, size_t ws_size,
                              hipStream_t stream)
{
    const float* x   = (const float*)d_in[0];
    const float* pos = (const float*)d_in[1];
    const float* Wq  = (const float*)d_in[2];
    const float* bq  = (const float*)d_in[3];
    const float* Wk  = (const float*)d_in[4];
    const float* bk  = (const float*)d_in[5];
    const float* Wv  = (const float*)d_in[6];
    const float* bv  = (const float*)d_in[7];
    const float* Wp  = (const float*)d_in[8];
    const float* u   = (const float*)d_in[9];
    const float* v   = (const float*)d_in[10];
    const float* Wo  = (const float*)d_in[11];
    const float* bo  = (const float*)d_in[12];
    char* wsb  = (char*)d_ws;
    float* out = (float*)d_out;

    // Workspace guard: need BY_PSH + >=1 head of shifted pos (44.6 MB min).
    if (ws_size < (size_t)BY_PSH + PSH_HEAD_BYTES) {
        zero_fill<<<(out_size + 255) / 256, 256, 0, stream>>>(out, out_size);
        return;
    }

    // 1. dtype prep
    conv_inputs<<<dim3(2048, 1, 2), 256, 0, stream>>>(x, pos, wsb);
    conv_wt<<<dim3(8, 8, 5), 256, 0, stream>>>(Wq, Wk, Wv, Wp, Wo, wsb);

    // 2. projections (fp16 MFMA)
    proj_mfma<<<dim3(32, 4, 4), 256, 0, stream>>>(bq, bk, bv, u, v, wsb);

    // 3. attention in head-chunks sized to workspace
    int c = (int)((ws_size - (size_t)BY_PSH) / (size_t)PSH_HEAD_BYTES);
    if (c < 1) c = 1;
    if (c > NBH) c = NBH;

    for (int g0 = 0; g0 < NBH; g0 += c) {
        int cc = (NBH - g0 < c) ? (NBH - g0) : c;
        pos_gemm<<<dim3(16, 16, cc), 256, 0, stream>>>(
            (const unsigned short*)(wsb + BY_QV),
            (const unsigned short*)(wsb + BY_PB),
            (unsigned short*)(wsb + BY_PSH), g0);
        attn_fused<<<dim3(cc * 128), 256, 0, stream>>>(
            (const unsigned short*)(wsb + BY_QU),
            (const unsigned short*)(wsb + BY_K),
            (const unsigned short*)(wsb + BY_VT),
            (const unsigned short*)(wsb + BY_PSH),
            (unsigned short*)(wsb + BY_CTX), g0);
    }

    // 4. output projection (fp16 MFMA, fp32 out)
    out_mfma<<<dim3(32, 4), 256, 0, stream>>>(bo, wsb, out);
}

// Round 11
// 353.511 us; speedup vs baseline: 1.3567x; 1.0221x over previous
//
#include <hip/hip_runtime.h>
#include <hip/hip_fp16.h>
#include <math.h>

// Transformer-XL relative multi-head attention, MI355X. B=2,S=2048,D=512,H=8,dh=64.
// Round-11: r10 pipeline, pos path restructured to remove the 67M scalar scatter
// stores (r10 pos_gemm ~150us, store-issue-bound):
//   a) pos_gemm stores RAW Ppos[q][j] coalesced (swapped operands -> aligned
//      ushort4 per lane).
//   b) attn_fused reads raw Ppos through the rel-shift flat-index trick
//      (validated r4-r6) with TWO aligned 8B loads per quad + per-lane 64-bit
//      funnel shifts: off=(3q+2)&3 is the flat index misalignment (constant per
//      lane), window halfs[off..off+4] give both k<=q (lo) and k>=q+2 (hi)
//      candidates; cndmask selects, k==q+1 -> 0.  Same values as r10's Psh.
//  1. conv_inputs : x,pos fp32 -> fp16.   2. conv_wt: 5 weights -> fp16 W^T.
//  3. proj_mfma   : QU(+u)/QV(+v), K, Pb [s][d]; VT [d][s]  (fp16 MFMA).
//  4. per head-chunk: pos_gemm -> raw Ppos fp16 ; attn_fused (r8 core) -> ctx fp16.
//  5. out_mfma    : out(fp32) = ctx @ Wo + bo.

#define S_LEN 2048
#define NH 8
#define DHD 64
#define DM 512
#define NBH 16
#define HEAD_ELEMS (S_LEN * DHD)
#define SS ((size_t)S_LEN * (size_t)S_LEN)

// workspace byte offsets
#define BY_QU  0u               // fp16 [16][2048][64]  4 MB
#define BY_QV  4194304u         // fp16 [16][2048][64]  4 MB
#define BY_K   8388608u         // fp16 [16][2048][64]  4 MB
#define BY_VT  12582912u        // fp16 [16][64][2048]  4 MB
#define BY_PB  16777216u        // fp16 [16][2048][64]  4 MB
#define BY_XH  20971520u        // fp16 [2][2048][512]  4 MB
#define BY_PH  25165824u        // fp16 [2][2048][512]  4 MB
#define BY_WT  29360128u        // fp16 [5][512][512] transposed, 2.62 MB
#define BY_CTX 31981568u        // fp16 [2][2048][512]  4 MB
#define BY_PP  36175872u        // fp16 [c][2048][2048] raw Ppos, 8.39 MB/head
#define PP_HEAD_BYTES 8388608u
#define WT_MAT_HALFS 262144u

typedef short v8s __attribute__((ext_vector_type(8)));
typedef float v4f __attribute__((ext_vector_type(4)));

static __device__ __forceinline__ unsigned short f2h(float f) {
    __half h = __float2half(f);
    return *reinterpret_cast<unsigned short*>(&h);
}
static __device__ __forceinline__ float h2f(unsigned short u) {
    __half h = *reinterpret_cast<__half*>(&u);
    return __half2float(h);
}

// ---------------------------------------------------------------------------
// conv_inputs: fp32 -> fp16, 4 els/thread. z: 0 = x, 1 = pos.
// ---------------------------------------------------------------------------
__global__ __launch_bounds__(256)
void conv_inputs(const float* __restrict__ x, const float* __restrict__ pos,
                 char* __restrict__ wsb)
{
    const float* src = blockIdx.z ? pos : x;
    unsigned short* dst = (unsigned short*)(wsb + (blockIdx.z ? BY_PH : BY_XH));
    int i = (blockIdx.x * 256 + threadIdx.x) * 4;
    float4 a = *(const float4*)(src + i);
    ushort4 p;
    p.x = f2h(a.x); p.y = f2h(a.y); p.z = f2h(a.z); p.w = f2h(a.w);
    *(ushort4*)(dst + i) = p;
}

// ---------------------------------------------------------------------------
// conv_wt: WT[m][n][k] = W_m[k][n] fp16. 64x64 LDS tile transpose.
// ---------------------------------------------------------------------------
__global__ __launch_bounds__(256)
void conv_wt(const float* __restrict__ Wq, const float* __restrict__ Wk,
             const float* __restrict__ Wv, const float* __restrict__ Wp,
             const float* __restrict__ Wo, char* __restrict__ wsb)
{
    __shared__ float T[64][65];
    const float* W = (blockIdx.z == 0) ? Wq : (blockIdx.z == 1) ? Wk :
                     (blockIdx.z == 2) ? Wv : (blockIdx.z == 3) ? Wp : Wo;
    unsigned short* WT = (unsigned short*)(wsb + BY_WT) + blockIdx.z * WT_MAT_HALFS;
    const int n0 = blockIdx.x * 64, k0 = blockIdx.y * 64;
    const int t = threadIdx.x;
#pragma unroll
    for (int i = 0; i < 4; ++i) {
        int f = t + i * 256;
        int row = f >> 4, c4 = f & 15;
        *(float4*)&T[row][c4 * 4] = *(const float4*)(W + (size_t)(k0 + row) * 512 + n0 + c4 * 4);
    }
    __syncthreads();
#pragma unroll
    for (int i = 0; i < 4; ++i) {
        int f = t + i * 256;
        int n = f >> 4, k4 = f & 15;
        ushort4 p;
        p.x = f2h(T[k4 * 4 + 0][n]); p.y = f2h(T[k4 * 4 + 1][n]);
        p.z = f2h(T[k4 * 4 + 2][n]); p.w = f2h(T[k4 * 4 + 3][n]);
        *(ushort4*)(WT + (size_t)(n0 + n) * 512 + k0 + k4 * 4) = p;
    }
}

// ---------------------------------------------------------------------------
// proj_mfma: all four projections via fp16 MFMA, no LDS, 4 waves = 2x2 64x64.
// grid (32, 4, 4): x = s-tile(128), y = d-tile(128), z = mode.
// modes 0(Q),1(K),3(P): SWAPPED  C[d][s]; mode 2(V): C[s][d] -> VT store.
// ---------------------------------------------------------------------------
__global__ __launch_bounds__(256)
void proj_mfma(const float* __restrict__ bq, const float* __restrict__ bk,
               const float* __restrict__ bvp,
               const float* __restrict__ uvec, const float* __restrict__ vvec,
               char* __restrict__ wsb)
{
    const int t = threadIdx.x;
    const int wave = t >> 6, lane = t & 63;
    const int quad = lane >> 4, l16 = lane & 15;
    const int wm = wave >> 1, wn = wave & 1;
    const int mode = blockIdx.z;
    const unsigned short* xh = (const unsigned short*)(wsb + BY_XH);
    const unsigned short* ph = (const unsigned short*)(wsb + BY_PH);
    const unsigned short* wt = (const unsigned short*)(wsb + BY_WT);

    v4f acc[4][4];
#pragma unroll
    for (int i = 0; i < 4; ++i)
#pragma unroll
        for (int j = 0; j < 4; ++j) acc[i][j] = (v4f){0.f, 0.f, 0.f, 0.f};

    if (mode != 2) {
        const int d0 = blockIdx.y * 128 + wm * 64;
        const int s0 = blockIdx.x * 128 + wn * 64;
        const int mat = (mode == 0) ? 0 : (mode == 1) ? 1 : 3;
        const unsigned short* A = wt + (size_t)mat * WT_MAT_HALFS;   // [d][k]
        const unsigned short* B = (mode == 3) ? ph : xh;             // [s][k]

        for (int kk = 0; kk < 16; ++kk) {
            v8s af[4], bf[4];
#pragma unroll
            for (int i = 0; i < 4; ++i) {
                af[i] = *(const v8s*)(A + (size_t)(d0 + i * 16 + l16) * 512 + kk * 32 + quad * 8);
                bf[i] = *(const v8s*)(B + (size_t)(s0 + i * 16 + l16) * 512 + kk * 32 + quad * 8);
            }
#pragma unroll
            for (int i = 0; i < 4; ++i)
#pragma unroll
                for (int j = 0; j < 4; ++j)
                    acc[i][j] = __builtin_amdgcn_mfma_f32_16x16x32_f16(af[i], bf[j], acc[i][j], 0, 0, 0);
        }

#pragma unroll
        for (int i = 0; i < 4; ++i) {
            int db = d0 + i * 16 + quad * 4;
            int h = db >> 6, dl = db & 63;
            float4 b4 = (mode == 3) ? make_float4(0.f, 0.f, 0.f, 0.f)
                        : (mode == 0) ? *(const float4*)(bq + db)
                                      : *(const float4*)(bk + db);
#pragma unroll
            for (int j = 0; j < 4; ++j) {
                int s = s0 + j * 16 + l16;
                int bb = s >> 11, srow = s & 2047;
                size_t o = ((size_t)(bb * NH + h) * S_LEN + srow) * DHD + dl;
                if (mode == 0) {
                    float4 u4 = *(const float4*)(uvec + db);
                    float4 v4 = *(const float4*)(vvec + db);
                    unsigned short* qu = (unsigned short*)(wsb + BY_QU);
                    unsigned short* qv = (unsigned short*)(wsb + BY_QV);
                    ushort4 pu, pv;
                    pu.x = f2h(acc[i][j][0] + b4.x + u4.x);
                    pu.y = f2h(acc[i][j][1] + b4.y + u4.y);
                    pu.z = f2h(acc[i][j][2] + b4.z + u4.z);
                    pu.w = f2h(acc[i][j][3] + b4.w + u4.w);
                    pv.x = f2h(acc[i][j][0] + b4.x + v4.x);
                    pv.y = f2h(acc[i][j][1] + b4.y + v4.y);
                    pv.z = f2h(acc[i][j][2] + b4.z + v4.z);
                    pv.w = f2h(acc[i][j][3] + b4.w + v4.w);
                    *(ushort4*)(qu + o) = pu;
                    *(ushort4*)(qv + o) = pv;
                } else {
                    unsigned short* dst = (unsigned short*)(wsb + (mode == 1 ? BY_K : BY_PB));
                    ushort4 pk;
                    pk.x = f2h(acc[i][j][0] + b4.x);
                    pk.y = f2h(acc[i][j][1] + b4.y);
                    pk.z = f2h(acc[i][j][2] + b4.z);
                    pk.w = f2h(acc[i][j][3] + b4.w);
                    *(ushort4*)(dst + o) = pk;
                }
            }
        }
    } else {
        const int s0 = blockIdx.x * 128 + wm * 64;
        const int d0 = blockIdx.y * 128 + wn * 64;
        const unsigned short* A = xh;                                 // [s][k]
        const unsigned short* B = wt + (size_t)2 * WT_MAT_HALFS;      // [d][k]

        for (int kk = 0; kk < 16; ++kk) {
            v8s af[4], bf[4];
#pragma unroll
            for (int i = 0; i < 4; ++i) {
                af[i] = *(const v8s*)(A + (size_t)(s0 + i * 16 + l16) * 512 + kk * 32 + quad * 8);
                bf[i] = *(const v8s*)(B + (size_t)(d0 + i * 16 + l16) * 512 + kk * 32 + quad * 8);
            }
#pragma unroll
            for (int i = 0; i < 4; ++i)
#pragma unroll
                for (int j = 0; j < 4; ++j)
                    acc[i][j] = __builtin_amdgcn_mfma_f32_16x16x32_f16(af[i], bf[j], acc[i][j], 0, 0, 0);
        }

        unsigned short* vt = (unsigned short*)(wsb + BY_VT);
#pragma unroll
        for (int j = 0; j < 4; ++j) {
            int d = d0 + j * 16 + l16;
            int h = d >> 6, dl = d & 63;
            float bval = bvp[d];
#pragma unroll
            for (int i = 0; i < 4; ++i) {
                int sb = s0 + i * 16 + quad * 4;
                int bb = sb >> 11, srow = sb & 2047;
                size_t o = ((size_t)(bb * NH + h) * DHD + dl) * S_LEN + srow;
                ushort4 pk;
                pk.x = f2h(acc[i][j][0] + bval);
                pk.y = f2h(acc[i][j][1] + bval);
                pk.z = f2h(acc[i][j][2] + bval);
                pk.w = f2h(acc[i][j][3] + bval);
                *(ushort4*)(vt + o) = pk;
            }
        }
    }
}

// ---------------------------------------------------------------------------
// pos GEMM: raw Ppos[q][j] = qv[q].pb[j], stored PLAIN and coalesced.
// SWAPPED operands: A = Pb rows (m-dim = j), B = QV rows (n-dim = q) ->
// C[j][q]: lane holds 4 consecutive j at fixed q -> aligned ushort4 store
// (j-base = quad*4, always 8B aligned).  16 store insts per 64x64 tile.
// ---------------------------------------------------------------------------
__global__ __launch_bounds__(256)
void pos_gemm(const unsigned short* __restrict__ qv,
              const unsigned short* __restrict__ pb,
              unsigned short* __restrict__ pp, int head_base)
{
    const int t = threadIdx.x;
    const int wave = t >> 6, lane = t & 63;
    const int quad = lane >> 4, l16 = lane & 15;
    const int wm = wave >> 1, wn = wave & 1;
    const int z = blockIdx.z, g = head_base + z;
    const int m0 = blockIdx.y * 128 + wm * 64;   // j-dim (Pb rows)
    const int n0 = blockIdx.x * 128 + wn * 64;   // q-dim (QV rows)

    const unsigned short* A = pb + (size_t)g * HEAD_ELEMS;   // [j][d]
    const unsigned short* B = qv + (size_t)g * HEAD_ELEMS;   // [q][d]
    unsigned short* out = pp + (size_t)z * SS;

    v8s af[4][2], bf[4][2];
#pragma unroll
    for (int i = 0; i < 4; ++i)
#pragma unroll
        for (int kk = 0; kk < 2; ++kk) {
            af[i][kk] = *(const v8s*)(A + (size_t)(m0 + i * 16 + l16) * DHD + kk * 32 + quad * 8);
            bf[i][kk] = *(const v8s*)(B + (size_t)(n0 + i * 16 + l16) * DHD + kk * 32 + quad * 8);
        }

#pragma unroll
    for (int i = 0; i < 4; ++i)
#pragma unroll
        for (int j = 0; j < 4; ++j) {
            v4f c = (v4f){0.f, 0.f, 0.f, 0.f};
            c = __builtin_amdgcn_mfma_f32_16x16x32_f16(af[i][0], bf[j][0], c, 0, 0, 0);
            c = __builtin_amdgcn_mfma_f32_16x16x32_f16(af[i][1], bf[j][1], c, 0, 0, 0);
            int jb = m0 + i * 16 + quad * 4;     // 4 consecutive j, 4-aligned
            int qcol = n0 + j * 16 + l16;
            ushort4 pk;
            pk.x = f2h(c[0]); pk.y = f2h(c[1]); pk.z = f2h(c[2]); pk.w = f2h(c[3]);
            *(ushort4*)(out + (size_t)qcol * S_LEN + jb) = pk;
        }
}

// ---------------------------------------------------------------------------
// Flash attention (r8 core). Pos scores read from RAW Ppos via the rel-shift
// flat-index trick: shifted[q][k] = flat[(q+1)*2047 + k - (k>=q+1)] (0 at
// k==q+1).  off = ((q+1)*2047-1)&3 = (3q+2)&3 is per-lane constant; two aligned
// 8B loads cover halfs [albase+kb, +8) = window [base+kb-1-off, ...]; 64-bit
// funnel shifts extract lo (k<=q: flat[base+k]) and hi (k>=q+2: flat[base+k-1]).
// Block 256 = 4 waves; q-tile [qt*16,+16); wave w owns keys [w*512,+512).
// ---------------------------------------------------------------------------
__global__ __launch_bounds__(256, 4)
void attn_fused(const unsigned short* __restrict__ qu,
                const unsigned short* __restrict__ kdat,
                const unsigned short* __restrict__ vtg,
                const unsigned short* __restrict__ pp,
                unsigned short* __restrict__ ctx, int head_base)
{
    __shared__ unsigned short SpAll[4][2304];
    __shared__ float MlAll[4][128];

    const int t = threadIdx.x;
    const int wave = t >> 6, lane = t & 63;
    const int quad = lane >> 4, l16 = lane & 15;
    const int z = blockIdx.x >> 7, qt = blockIdx.x & 127;
    const int g = head_base + z;
    const int q0 = qt * 16;
    const int q = q0 + l16;

    const unsigned short* QU = qu   + (size_t)g * HEAD_ELEMS;
    const unsigned short* Kg = kdat + (size_t)g * HEAD_ELEMS;
    const unsigned short* Vg = vtg  + (size_t)g * HEAD_ELEMS;
    const unsigned short* Pg = pp   + (size_t)z * SS;
    unsigned short* Sp = &SpAll[wave][0];

    const v8s bq0 = *(const v8s*)(QU + (size_t)(q0 + l16) * DHD + quad * 8);
    const v8s bq1 = *(const v8s*)(QU + (size_t)(q0 + l16) * DHD + 32 + quad * 8);

    float m_run = -1e30f, l_run = 0.f;
    v4f accv[4];
#pragma unroll
    for (int r = 0; r < 4; ++r) accv[r] = (v4f){0.f, 0.f, 0.f, 0.f};
    const float scale = 0.04419417382415922f;

    const int off = (3 * q + 2) & 3;                       // flat misalignment
    const int sh = off * 16;
    const size_t albase = (size_t)(q + 1) * 2047 - 1 - off; // 4-half aligned

    for (int kt = 0; kt < 4; ++kt) {
        const int k0 = wave * 512 + kt * 128;

        // pos window loads (aligned 8B x2 per quad), issued early
        uint2 wA[8], wB[8];
#pragma unroll
        for (int nt = 0; nt < 8; ++nt) {
            const size_t a = albase + (size_t)(k0 + nt * 16 + quad * 4);
            wA[nt] = *(const uint2*)(Pg + a);
            wB[nt] = *(const uint2*)(Pg + a + 4);
        }

        v4f sacc[8];
#pragma unroll
        for (int nt = 0; nt < 8; ++nt) {
            v8s a0 = *(const v8s*)(Kg + (size_t)(k0 + nt * 16 + l16) * DHD + quad * 8);
            v8s a1 = *(const v8s*)(Kg + (size_t)(k0 + nt * 16 + l16) * DHD + 32 + quad * 8);
            v4f c = (v4f){0.f, 0.f, 0.f, 0.f};
            c = __builtin_amdgcn_mfma_f32_16x16x32_f16(a0, bq0, c, 0, 0, 0);
            c = __builtin_amdgcn_mfma_f32_16x16x32_f16(a1, bq1, c, 0, 0, 0);
            sacc[nt] = c;
        }

        // add rel-shifted pos (funnel-shift window extract) and scale; local max
        float tm = -1e30f;
#pragma unroll
        for (int nt = 0; nt < 8; ++nt) {
            int kb = k0 + nt * 16 + quad * 4;
            unsigned long long c01 = ((unsigned long long)wA[nt].y << 32) | wA[nt].x;
            unsigned long long c12 = ((unsigned long long)wB[nt].x << 32) | wA[nt].y;
            unsigned long long c23 = ((unsigned long long)wB[nt].y << 32) | wB[nt].x;
            unsigned dA = (unsigned)(c01 >> sh);   // halfs off, off+1
            unsigned dB = (unsigned)(c12 >> sh);   // halfs off+2, off+3
            unsigned dC = (unsigned)(c23 >> sh);   // halfs off+4, off+5
            unsigned short lo_[4] = { (unsigned short)(dA >> 16),
                                      (unsigned short)(dB & 0xffff),
                                      (unsigned short)(dB >> 16),
                                      (unsigned short)(dC & 0xffff) };
            unsigned short hi_[4] = { (unsigned short)(dA & 0xffff),
                                      (unsigned short)(dA >> 16),
                                      (unsigned short)(dB & 0xffff),
                                      (unsigned short)(dB >> 16) };
#pragma unroll
            for (int reg = 0; reg < 4; ++reg) {
                int k = kb + reg;
                float pv = (k <= q) ? h2f(lo_[reg])
                         : ((k == q + 1) ? 0.f : h2f(hi_[reg]));
                sacc[nt][reg] = (sacc[nt][reg] + pv) * scale;
                tm = fmaxf(tm, sacc[nt][reg]);
            }
        }
        tm = fmaxf(tm, __shfl_xor(tm, 16));
        tm = fmaxf(tm, __shfl_xor(tm, 32));
        float mn = fmaxf(m_run, tm);
        float al = __expf(m_run - mn);
        float rs = 0.f;
#pragma unroll
        for (int nt = 0; nt < 8; ++nt)
#pragma unroll
            for (int reg = 0; reg < 4; ++reg) {
                sacc[nt][reg] = __expf(sacc[nt][reg] - mn);
                rs += sacc[nt][reg];
            }
        rs += __shfl_xor(rs, 16);
        rs += __shfl_xor(rs, 32);
        l_run = l_run * al + rs;
        m_run = mn;

        float alr[4];
#pragma unroll
        for (int reg = 0; reg < 4; ++reg) alr[reg] = __shfl(al, quad * 4 + reg);
#pragma unroll
        for (int ntd = 0; ntd < 4; ++ntd)
#pragma unroll
            for (int reg = 0; reg < 4; ++reg) accv[ntd][reg] *= alr[reg];

#pragma unroll
        for (int nt = 0; nt < 8; ++nt) {
            ushort4 pk;
            pk.x = f2h(sacc[nt][0]); pk.y = f2h(sacc[nt][1]);
            pk.z = f2h(sacc[nt][2]); pk.w = f2h(sacc[nt][3]);
            *(ushort4*)&Sp[l16 * 136 + nt * 16 + quad * 4] = pk;
        }

#pragma unroll
        for (int c4 = 0; c4 < 4; ++c4) {
            v8s ap = *(const v8s*)&Sp[l16 * 136 + c4 * 32 + quad * 8];
#pragma unroll
            for (int ntd = 0; ntd < 4; ++ntd) {
                v8s bv8 = *(const v8s*)(Vg + (size_t)(ntd * 16 + l16) * S_LEN +
                                        k0 + c4 * 32 + quad * 8);
                accv[ntd] = __builtin_amdgcn_mfma_f32_16x16x32_f16(ap, bv8, accv[ntd], 0, 0, 0);
            }
        }
    }

    MlAll[wave][lane * 2]     = m_run;
    MlAll[wave][lane * 2 + 1] = l_run;
    if (wave != 0) {
        float* accSlot = (float*)&SpAll[wave][0];
#pragma unroll
        for (int ntd = 0; ntd < 4; ++ntd)
#pragma unroll
            for (int reg = 0; reg < 4; ++reg)
                accSlot[lane * 16 + ntd * 4 + reg] = accv[ntd][reg];
    }
    __syncthreads();
    if (wave == 0) {
        const int bb = g >> 3, h = g & 7;
        float ew[4][4], inv[4];
#pragma unroll
        for (int reg = 0; reg < 4; ++reg) {
            int qi = quad * 4 + reg;
            float mw[4], lw[4];
#pragma unroll
            for (int w = 0; w < 4; ++w) {
                mw[w] = MlAll[w][qi * 2];
                lw[w] = MlAll[w][qi * 2 + 1];
            }
            float ms = fmaxf(fmaxf(mw[0], mw[1]), fmaxf(mw[2], mw[3]));
            float lt = 0.f;
#pragma unroll
            for (int w = 0; w < 4; ++w) {
                ew[reg][w] = __expf(mw[w] - ms);
                lt += lw[w] * ew[reg][w];
            }
            inv[reg] = 1.f / lt;
        }
#pragma unroll
        for (int ntd = 0; ntd < 4; ++ntd) {
#pragma unroll
            for (int reg = 0; reg < 4; ++reg) {
                float o = accv[ntd][reg] * ew[reg][0];
#pragma unroll
                for (int w = 1; w < 4; ++w) {
                    const float* slot = (const float*)&SpAll[w][0];
                    o += slot[lane * 16 + ntd * 4 + reg] * ew[reg][w];
                }
                int qq = q0 + quad * 4 + reg;
                ctx[((size_t)(bb * S_LEN + qq)) * DM + h * DHD + ntd * 16 + l16] =
                    f2h(o * inv[reg]);
            }
        }
    }
}

// ---------------------------------------------------------------------------
// out_mfma: out(fp32)[s][n] = ctx(fp16) @ Wo + bo.  SWAPPED: C[n][s] ->
// float4 stores.  grid (32, 4): x = s-tile(128), y = n-tile(128).
// ---------------------------------------------------------------------------
__global__ __launch_bounds__(256)
void out_mfma(const float* __restrict__ bo, const char* __restrict__ wsb,
              float* __restrict__ out)
{
    const int t = threadIdx.x;
    const int wave = t >> 6, lane = t & 63;
    const int quad = lane >> 4, l16 = lane & 15;
    const int wm = wave >> 1, wn = wave & 1;
    const int n0 = blockIdx.y * 128 + wm * 64;
    const int s0 = blockIdx.x * 128 + wn * 64;
    const unsigned short* A = (const unsigned short*)(wsb + BY_WT) + (size_t)4 * WT_MAT_HALFS;
    const unsigned short* B = (const unsigned short*)(wsb + BY_CTX);

    v4f acc[4][4];
#pragma unroll
    for (int i = 0; i < 4; ++i)
#pragma unroll
        for (int j = 0; j < 4; ++j) acc[i][j] = (v4f){0.f, 0.f, 0.f, 0.f};

    for (int kk = 0; kk < 16; ++kk) {
        v8s af[4], bf[4];
#pragma unroll
        for (int i = 0; i < 4; ++i) {
            af[i] = *(const v8s*)(A + (size_t)(n0 + i * 16 + l16) * 512 + kk * 32 + quad * 8);
            bf[i] = *(const v8s*)(B + (size_t)(s0 + i * 16 + l16) * 512 + kk * 32 + quad * 8);
        }
#pragma unroll
        for (int i = 0; i < 4; ++i)
#pragma unroll
            for (int j = 0; j < 4; ++j)
                acc[i][j] = __builtin_amdgcn_mfma_f32_16x16x32_f16(af[i], bf[j], acc[i][j], 0, 0, 0);
    }

#pragma unroll
    for (int i = 0; i < 4; ++i) {
        int nb = n0 + i * 16 + quad * 4;
        float4 b4 = *(const float4*)(bo + nb);
#pragma unroll
        for (int j = 0; j < 4; ++j) {
            int s = s0 + j * 16 + l16;
            *(float4*)(out + (size_t)s * DM + nb) =
                make_float4(acc[i][j][0] + b4.x, acc[i][j][1] + b4.y,
                            acc[i][j][2] + b4.z, acc[i][j][3] + b4.w);
        }
    }
}

// Fallback when ws_size is insufficient: clean mismatch instead of OOB writes.
__global__ void zero_fill(float* __restrict__ p, int n)
{
    int i = blockIdx.x * 256 + threadIdx.x;
    if (i < n) p[i] = 0.f;
}

// ---------------------------------------------------------------------------
extern "C" void kernel_launch(void* const* d_in, const int* in_sizes, int n_in,
                              void* d_out, int out_size, void* d_ws, size_t ws_size,
                              hipStream_t stream)
{
    const float* x   = (const float*)d_in[0];
    const float* pos = (const float*)d_in[1];
    const float* Wq  = (const float*)d_in[2];
    const float* bq  = (const float*)d_in[3];
    const float* Wk  = (const float*)d_in[4];
    const float* bk  = (const float*)d_in[5];
    const float* Wv  = (const float*)d_in[6];
    const float* bv  = (const float*)d_in[7];
    const float* Wp  = (const float*)d_in[8];
    const float* u   = (const float*)d_in[9];
    const float* v   = (const float*)d_in[10];
    const float* Wo  = (const float*)d_in[11];
    const float* bo  = (const float*)d_in[12];
    char* wsb  = (char*)d_ws;
    float* out = (float*)d_out;

    // Workspace guard: need BY_PP + >=1 head of raw Ppos (44.6 MB min).
    if (ws_size < (size_t)BY_PP + PP_HEAD_BYTES) {
        zero_fill<<<(out_size + 255) / 256, 256, 0, stream>>>(out, out_size);
        return;
    }

    // 1. dtype prep
    conv_inputs<<<dim3(2048, 1, 2), 256, 0, stream>>>(x, pos, wsb);
    conv_wt<<<dim3(8, 8, 5), 256, 0, stream>>>(Wq, Wk, Wv, Wp, Wo, wsb);

    // 2. projections (fp16 MFMA)
    proj_mfma<<<dim3(32, 4, 4), 256, 0, stream>>>(bq, bk, bv, u, v, wsb);

    // 3. attention in head-chunks sized to workspace
    int c = (int)((ws_size - (size_t)BY_PP) / (size_t)PP_HEAD_BYTES);
    if (c < 1) c = 1;
    if (c > NBH) c = NBH;

    for (int g0 = 0; g0 < NBH; g0 += c) {
        int cc = (NBH - g0 < c) ? (NBH - g0) : c;
        pos_gemm<<<dim3(16, 16, cc), 256, 0, stream>>>(
            (const unsigned short*)(wsb + BY_QV),
            (const unsigned short*)(wsb + BY_PB),
            (unsigned short*)(wsb + BY_PP), g0);
        attn_fused<<<dim3(cc * 128), 256, 0, stream>>>(
            (const unsigned short*)(wsb + BY_QU),
            (const unsigned short*)(wsb + BY_K),
            (const unsigned short*)(wsb + BY_VT),
            (const unsigned short*)(wsb + BY_PP),
            (unsigned short*)(wsb + BY_CTX), g0);
    }

    // 4. output projection (fp16 MFMA, fp32 out)
    out_mfma<<<dim3(32, 4), 256, 0, stream>>>(bo, wsb, out);
}

// Round 12
// 346.300 us; speedup vs baseline: 1.3849x; 1.0208x over previous
//
#include <hip/hip_runtime.h>
#include <hip/hip_fp16.h>
#include <math.h>

// Transformer-XL relative multi-head attention, MI355X. B=2,S=2048,D=512,H=8,dh=64.
// Round-12: r11 pipeline; attn_fused Ppos stream moved to ASYNC global_load_lds.
//   r11 diagnosis: attn is bound by the 134 MB single-use Ppos HBM stream at
//   ~890 GB/s effective -> per-wave MLP too low (VGPR-64 just-in-time loads;
//   r9 showed VGPR prefetch trades occupancy 1:1).  Fix: 5x global_load_lds
//   (width 16) per wave per k-tile stage the per-row rel-shift windows into a
//   wave-private LDS buffer (per-lane global gather, wave-uniform LDS dest +
//   lane*16 -- chunk layout matches the HW mapping).  5 KB/wave in flight at
//   zero VGPR cost; single buffer is safe (in-order issue; explicit
//   s_waitcnt vmcnt(0) before extraction, lgkmcnt(0) before next issue).
//   Funnel-shift extraction identical to r11 -> bit-identical results.
//  1. conv_inputs : x,pos fp32 -> fp16.   2. conv_wt: 5 weights -> fp16 W^T.
//  3. proj_mfma   : QU(+u)/QV(+v), K, Pb [s][d]; VT [d][s]  (fp16 MFMA).
//  4. per head-chunk: pos_gemm -> raw Ppos fp16 ; attn_fused -> ctx fp16.
//  5. out_mfma    : out(fp32) = ctx @ Wo + bo.

#define S_LEN 2048
#define NH 8
#define DHD 64
#define DM 512
#define NBH 16
#define HEAD_ELEMS (S_LEN * DHD)
#define SS ((size_t)S_LEN * (size_t)S_LEN)

// workspace byte offsets
#define BY_QU  0u               // fp16 [16][2048][64]  4 MB
#define BY_QV  4194304u         // fp16 [16][2048][64]  4 MB
#define BY_K   8388608u         // fp16 [16][2048][64]  4 MB
#define BY_VT  12582912u        // fp16 [16][64][2048]  4 MB
#define BY_PB  16777216u        // fp16 [16][2048][64]  4 MB
#define BY_XH  20971520u        // fp16 [2][2048][512]  4 MB
#define BY_PH  25165824u        // fp16 [2][2048][512]  4 MB
#define BY_WT  29360128u        // fp16 [5][512][512] transposed, 2.62 MB
#define BY_CTX 31981568u        // fp16 [2][2048][512]  4 MB
#define BY_PP  36175872u        // fp16 [c][2048][2048] raw Ppos, 8.39 MB/head
#define PP_HEAD_BYTES 8388608u
#define WT_MAT_HALFS 262144u

typedef short v8s __attribute__((ext_vector_type(8)));
typedef float v4f __attribute__((ext_vector_type(4)));

static __device__ __forceinline__ unsigned short f2h(float f) {
    __half h = __float2half(f);
    return *reinterpret_cast<unsigned short*>(&h);
}
static __device__ __forceinline__ float h2f(unsigned short u) {
    __half h = *reinterpret_cast<__half*>(&u);
    return __half2float(h);
}

// ---------------------------------------------------------------------------
// conv_inputs: fp32 -> fp16, 4 els/thread. z: 0 = x, 1 = pos.
// ---------------------------------------------------------------------------
__global__ __launch_bounds__(256)
void conv_inputs(const float* __restrict__ x, const float* __restrict__ pos,
                 char* __restrict__ wsb)
{
    const float* src = blockIdx.z ? pos : x;
    unsigned short* dst = (unsigned short*)(wsb + (blockIdx.z ? BY_PH : BY_XH));
    int i = (blockIdx.x * 256 + threadIdx.x) * 4;
    float4 a = *(const float4*)(src + i);
    ushort4 p;
    p.x = f2h(a.x); p.y = f2h(a.y); p.z = f2h(a.z); p.w = f2h(a.w);
    *(ushort4*)(dst + i) = p;
}

// ---------------------------------------------------------------------------
// conv_wt: WT[m][n][k] = W_m[k][n] fp16. 64x64 LDS tile transpose.
// ---------------------------------------------------------------------------
__global__ __launch_bounds__(256)
void conv_wt(const float* __restrict__ Wq, const float* __restrict__ Wk,
             const float* __restrict__ Wv, const float* __restrict__ Wp,
             const float* __restrict__ Wo, char* __restrict__ wsb)
{
    __shared__ float T[64][65];
    const float* W = (blockIdx.z == 0) ? Wq : (blockIdx.z == 1) ? Wk :
                     (blockIdx.z == 2) ? Wv : (blockIdx.z == 3) ? Wp : Wo;
    unsigned short* WT = (unsigned short*)(wsb + BY_WT) + blockIdx.z * WT_MAT_HALFS;
    const int n0 = blockIdx.x * 64, k0 = blockIdx.y * 64;
    const int t = threadIdx.x;
#pragma unroll
    for (int i = 0; i < 4; ++i) {
        int f = t + i * 256;
        int row = f >> 4, c4 = f & 15;
        *(float4*)&T[row][c4 * 4] = *(const float4*)(W + (size_t)(k0 + row) * 512 + n0 + c4 * 4);
    }
    __syncthreads();
#pragma unroll
    for (int i = 0; i < 4; ++i) {
        int f = t + i * 256;
        int n = f >> 4, k4 = f & 15;
        ushort4 p;
        p.x = f2h(T[k4 * 4 + 0][n]); p.y = f2h(T[k4 * 4 + 1][n]);
        p.z = f2h(T[k4 * 4 + 2][n]); p.w = f2h(T[k4 * 4 + 3][n]);
        *(ushort4*)(WT + (size_t)(n0 + n) * 512 + k0 + k4 * 4) = p;
    }
}

// ---------------------------------------------------------------------------
// proj_mfma: all four projections via fp16 MFMA, no LDS, 4 waves = 2x2 64x64.
// modes 0(Q),1(K),3(P): SWAPPED C[d][s]; mode 2(V): C[s][d] -> VT store.
// ---------------------------------------------------------------------------
__global__ __launch_bounds__(256)
void proj_mfma(const float* __restrict__ bq, const float* __restrict__ bk,
               const float* __restrict__ bvp,
               const float* __restrict__ uvec, const float* __restrict__ vvec,
               char* __restrict__ wsb)
{
    const int t = threadIdx.x;
    const int wave = t >> 6, lane = t & 63;
    const int quad = lane >> 4, l16 = lane & 15;
    const int wm = wave >> 1, wn = wave & 1;
    const int mode = blockIdx.z;
    const unsigned short* xh = (const unsigned short*)(wsb + BY_XH);
    const unsigned short* ph = (const unsigned short*)(wsb + BY_PH);
    const unsigned short* wt = (const unsigned short*)(wsb + BY_WT);

    v4f acc[4][4];
#pragma unroll
    for (int i = 0; i < 4; ++i)
#pragma unroll
        for (int j = 0; j < 4; ++j) acc[i][j] = (v4f){0.f, 0.f, 0.f, 0.f};

    if (mode != 2) {
        const int d0 = blockIdx.y * 128 + wm * 64;
        const int s0 = blockIdx.x * 128 + wn * 64;
        const int mat = (mode == 0) ? 0 : (mode == 1) ? 1 : 3;
        const unsigned short* A = wt + (size_t)mat * WT_MAT_HALFS;   // [d][k]
        const unsigned short* B = (mode == 3) ? ph : xh;             // [s][k]

        for (int kk = 0; kk < 16; ++kk) {
            v8s af[4], bf[4];
#pragma unroll
            for (int i = 0; i < 4; ++i) {
                af[i] = *(const v8s*)(A + (size_t)(d0 + i * 16 + l16) * 512 + kk * 32 + quad * 8);
                bf[i] = *(const v8s*)(B + (size_t)(s0 + i * 16 + l16) * 512 + kk * 32 + quad * 8);
            }
#pragma unroll
            for (int i = 0; i < 4; ++i)
#pragma unroll
                for (int j = 0; j < 4; ++j)
                    acc[i][j] = __builtin_amdgcn_mfma_f32_16x16x32_f16(af[i], bf[j], acc[i][j], 0, 0, 0);
        }

#pragma unroll
        for (int i = 0; i < 4; ++i) {
            int db = d0 + i * 16 + quad * 4;
            int h = db >> 6, dl = db & 63;
            float4 b4 = (mode == 3) ? make_float4(0.f, 0.f, 0.f, 0.f)
                        : (mode == 0) ? *(const float4*)(bq + db)
                                      : *(const float4*)(bk + db);
#pragma unroll
            for (int j = 0; j < 4; ++j) {
                int s = s0 + j * 16 + l16;
                int bb = s >> 11, srow = s & 2047;
                size_t o = ((size_t)(bb * NH + h) * S_LEN + srow) * DHD + dl;
                if (mode == 0) {
                    float4 u4 = *(const float4*)(uvec + db);
                    float4 v4 = *(const float4*)(vvec + db);
                    unsigned short* qu = (unsigned short*)(wsb + BY_QU);
                    unsigned short* qv = (unsigned short*)(wsb + BY_QV);
                    ushort4 pu, pv;
                    pu.x = f2h(acc[i][j][0] + b4.x + u4.x);
                    pu.y = f2h(acc[i][j][1] + b4.y + u4.y);
                    pu.z = f2h(acc[i][j][2] + b4.z + u4.z);
                    pu.w = f2h(acc[i][j][3] + b4.w + u4.w);
                    pv.x = f2h(acc[i][j][0] + b4.x + v4.x);
                    pv.y = f2h(acc[i][j][1] + b4.y + v4.y);
                    pv.z = f2h(acc[i][j][2] + b4.z + v4.z);
                    pv.w = f2h(acc[i][j][3] + b4.w + v4.w);
                    *(ushort4*)(qu + o) = pu;
                    *(ushort4*)(qv + o) = pv;
                } else {
                    unsigned short* dst = (unsigned short*)(wsb + (mode == 1 ? BY_K : BY_PB));
                    ushort4 pk;
                    pk.x = f2h(acc[i][j][0] + b4.x);
                    pk.y = f2h(acc[i][j][1] + b4.y);
                    pk.z = f2h(acc[i][j][2] + b4.z);
                    pk.w = f2h(acc[i][j][3] + b4.w);
                    *(ushort4*)(dst + o) = pk;
                }
            }
        }
    } else {
        const int s0 = blockIdx.x * 128 + wm * 64;
        const int d0 = blockIdx.y * 128 + wn * 64;
        const unsigned short* A = xh;                                 // [s][k]
        const unsigned short* B = wt + (size_t)2 * WT_MAT_HALFS;      // [d][k]

        for (int kk = 0; kk < 16; ++kk) {
            v8s af[4], bf[4];
#pragma unroll
            for (int i = 0; i < 4; ++i) {
                af[i] = *(const v8s*)(A + (size_t)(s0 + i * 16 + l16) * 512 + kk * 32 + quad * 8);
                bf[i] = *(const v8s*)(B + (size_t)(d0 + i * 16 + l16) * 512 + kk * 32 + quad * 8);
            }
#pragma unroll
            for (int i = 0; i < 4; ++i)
#pragma unroll
                for (int j = 0; j < 4; ++j)
                    acc[i][j] = __builtin_amdgcn_mfma_f32_16x16x32_f16(af[i], bf[j], acc[i][j], 0, 0, 0);
        }

        unsigned short* vt = (unsigned short*)(wsb + BY_VT);
#pragma unroll
        for (int j = 0; j < 4; ++j) {
            int d = d0 + j * 16 + l16;
            int h = d >> 6, dl = d & 63;
            float bval = bvp[d];
#pragma unroll
            for (int i = 0; i < 4; ++i) {
                int sb = s0 + i * 16 + quad * 4;
                int bb = sb >> 11, srow = sb & 2047;
                size_t o = ((size_t)(bb * NH + h) * DHD + dl) * S_LEN + srow;
                ushort4 pk;
                pk.x = f2h(acc[i][j][0] + bval);
                pk.y = f2h(acc[i][j][1] + bval);
                pk.z = f2h(acc[i][j][2] + bval);
                pk.w = f2h(acc[i][j][3] + bval);
                *(ushort4*)(vt + o) = pk;
            }
        }
    }
}

// ---------------------------------------------------------------------------
// pos GEMM: raw Ppos[q][j] = qv[q].pb[j], stored plain (r11).
// SWAPPED: C[j][q], lane holds 4 consecutive j at fixed q -> ushort4 stores.
// ---------------------------------------------------------------------------
__global__ __launch_bounds__(256)
void pos_gemm(const unsigned short* __restrict__ qv,
              const unsigned short* __restrict__ pb,
              unsigned short* __restrict__ pp, int head_base)
{
    const int t = threadIdx.x;
    const int wave = t >> 6, lane = t & 63;
    const int quad = lane >> 4, l16 = lane & 15;
    const int wm = wave >> 1, wn = wave & 1;
    const int z = blockIdx.z, g = head_base + z;
    const int m0 = blockIdx.y * 128 + wm * 64;   // j-dim (Pb rows)
    const int n0 = blockIdx.x * 128 + wn * 64;   // q-dim (QV rows)

    const unsigned short* A = pb + (size_t)g * HEAD_ELEMS;   // [j][d]
    const unsigned short* B = qv + (size_t)g * HEAD_ELEMS;   // [q][d]
    unsigned short* out = pp + (size_t)z * SS;

    v8s af[4][2], bf[4][2];
#pragma unroll
    for (int i = 0; i < 4; ++i)
#pragma unroll
        for (int kk = 0; kk < 2; ++kk) {
            af[i][kk] = *(const v8s*)(A + (size_t)(m0 + i * 16 + l16) * DHD + kk * 32 + quad * 8);
            bf[i][kk] = *(const v8s*)(B + (size_t)(n0 + i * 16 + l16) * DHD + kk * 32 + quad * 8);
        }

#pragma unroll
    for (int i = 0; i < 4; ++i)
#pragma unroll
        for (int j = 0; j < 4; ++j) {
            v4f c = (v4f){0.f, 0.f, 0.f, 0.f};
            c = __builtin_amdgcn_mfma_f32_16x16x32_f16(af[i][0], bf[j][0], c, 0, 0, 0);
            c = __builtin_amdgcn_mfma_f32_16x16x32_f16(af[i][1], bf[j][1], c, 0, 0, 0);
            int jb = m0 + i * 16 + quad * 4;
            int qcol = n0 + j * 16 + l16;
            ushort4 pk;
            pk.x = f2h(c[0]); pk.y = f2h(c[1]); pk.z = f2h(c[2]); pk.w = f2h(c[3]);
            *(ushort4*)(out + (size_t)qcol * S_LEN + jb) = pk;
        }
}

// ---------------------------------------------------------------------------
// Flash attention (r8 core) with ASYNC Ppos staging.
// Per wave per k-tile: 5x global_load_lds (width 16) gather each q-row's
// rel-shift window (16B-aligned base, 20 chunks/row of 8 halfs) into a
// wave-private LDS buffer: chunk c of row l16 at byte
//   (c>>2)*1024 + (c&3)*256 + l16*16      (inst j covers chunks j*4+quad).
// Extraction (funnel shifts, identical values to r11) reads buffer-local
// idx = rm + nt*16 + quad*4 where rm = albase&7.
// Single buffer: s_waitcnt vmcnt(0) before extraction; lgkmcnt(0) before
// issuing the next tile's DMA.  LDS 40960 B -> exactly 4 blocks/CU.
// ---------------------------------------------------------------------------
__global__ __launch_bounds__(256, 4)
void attn_fused(const unsigned short* __restrict__ qu,
                const unsigned short* __restrict__ kdat,
                const unsigned short* __restrict__ vtg,
                const unsigned short* __restrict__ pp,
                unsigned short* __restrict__ ctx, int head_base)
{
    __shared__ unsigned short SpAll[4][2304];
    __shared__ float MlAll[4][128];
    __shared__ __align__(16) unsigned short PosB[4][2560];  // 5 KB/wave

    const int t = threadIdx.x;
    const int wave = t >> 6, lane = t & 63;
    const int quad = lane >> 4, l16 = lane & 15;
    const int z = blockIdx.x >> 7, qt = blockIdx.x & 127;
    const int g = head_base + z;
    const int q0 = qt * 16;
    const int q = q0 + l16;

    const unsigned short* QU = qu   + (size_t)g * HEAD_ELEMS;
    const unsigned short* Kg = kdat + (size_t)g * HEAD_ELEMS;
    const unsigned short* Vg = vtg  + (size_t)g * HEAD_ELEMS;
    const unsigned short* Pg = pp   + (size_t)z * SS;
    unsigned short* Sp = &SpAll[wave][0];
    unsigned short* pbuf = &PosB[wave][0];

    const int off = (3 * q + 2) & 3;
    const int sh = off * 16;
    const size_t albase = (size_t)(q + 1) * 2047 - 1 - off;
    const int rm = (int)(albase & 7);                       // {0,4}
    const unsigned short* gdma = Pg + (albase - rm);        // 16B-aligned row base

#define ISSUE_POS(K0)                                                         \
    {                                                                         \
        _Pragma("unroll")                                                     \
        for (int jj = 0; jj < 5; ++jj)                                        \
            __builtin_amdgcn_global_load_lds(                                 \
                (const __attribute__((address_space(1))) unsigned int*)       \
                    (gdma + (K0) + (jj * 4 + quad) * 8),                      \
                (__attribute__((address_space(3))) unsigned int*)             \
                    (pbuf + jj * 512),                                        \
                16, 0, 0);                                                    \
    }

    // issue tile 0 DMA immediately
    ISSUE_POS(wave * 512)

    const v8s bq0 = *(const v8s*)(QU + (size_t)(q0 + l16) * DHD + quad * 8);
    const v8s bq1 = *(const v8s*)(QU + (size_t)(q0 + l16) * DHD + 32 + quad * 8);

    float m_run = -1e30f, l_run = 0.f;
    v4f accv[4];
#pragma unroll
    for (int r = 0; r < 4; ++r) accv[r] = (v4f){0.f, 0.f, 0.f, 0.f};
    const float scale = 0.04419417382415922f;

    for (int kt = 0; kt < 4; ++kt) {
        const int k0 = wave * 512 + kt * 128;

        // QK^T
        v4f sacc[8];
#pragma unroll
        for (int nt = 0; nt < 8; ++nt) {
            v8s a0 = *(const v8s*)(Kg + (size_t)(k0 + nt * 16 + l16) * DHD + quad * 8);
            v8s a1 = *(const v8s*)(Kg + (size_t)(k0 + nt * 16 + l16) * DHD + 32 + quad * 8);
            v4f c = (v4f){0.f, 0.f, 0.f, 0.f};
            c = __builtin_amdgcn_mfma_f32_16x16x32_f16(a0, bq0, c, 0, 0, 0);
            c = __builtin_amdgcn_mfma_f32_16x16x32_f16(a1, bq1, c, 0, 0, 0);
            sacc[nt] = c;
        }

        // DMA for this tile complete
        __builtin_amdgcn_s_waitcnt(0x0f70);   // vmcnt(0)

        // add rel-shifted pos from LDS (funnel-shift extract) + scale; local max
        float tm = -1e30f;
#pragma unroll
        for (int nt = 0; nt < 8; ++nt) {
            int kb = k0 + nt * 16 + quad * 4;
            int idx = rm + nt * 16 + quad * 4;
            int i1 = idx + 4;
            int c0 = idx >> 3, o0 = idx & 7;
            int c1 = i1 >> 3, o1 = i1 & 7;
            uint2 wAv = *(const uint2*)((const char*)pbuf +
                         (c0 >> 2) * 1024 + (c0 & 3) * 256 + l16 * 16 + o0 * 2);
            uint2 wBv = *(const uint2*)((const char*)pbuf +
                         (c1 >> 2) * 1024 + (c1 & 3) * 256 + l16 * 16 + o1 * 2);
            unsigned long long c01 = ((unsigned long long)wAv.y << 32) | wAv.x;
            unsigned long long c12 = ((unsigned long long)wBv.x << 32) | wAv.y;
            unsigned long long c23 = ((unsigned long long)wBv.y << 32) | wBv.x;
            unsigned dA = (unsigned)(c01 >> sh);
            unsigned dB = (unsigned)(c12 >> sh);
            unsigned dC = (unsigned)(c23 >> sh);
            unsigned short lo_[4] = { (unsigned short)(dA >> 16),
                                      (unsigned short)(dB & 0xffff),
                                      (unsigned short)(dB >> 16),
                                      (unsigned short)(dC & 0xffff) };
            unsigned short hi_[4] = { (unsigned short)(dA & 0xffff),
                                      (unsigned short)(dA >> 16),
                                      (unsigned short)(dB & 0xffff),
                                      (unsigned short)(dB >> 16) };
#pragma unroll
            for (int reg = 0; reg < 4; ++reg) {
                int k = kb + reg;
                float pv = (k <= q) ? h2f(lo_[reg])
                         : ((k == q + 1) ? 0.f : h2f(hi_[reg]));
                sacc[nt][reg] = (sacc[nt][reg] + pv) * scale;
                tm = fmaxf(tm, sacc[nt][reg]);
            }
        }

        // extraction reads retired -> safe to refill the single buffer
        __builtin_amdgcn_s_waitcnt(0xc07f);   // lgkmcnt(0)
        if (kt < 3) ISSUE_POS(k0 + 128)

        tm = fmaxf(tm, __shfl_xor(tm, 16));
        tm = fmaxf(tm, __shfl_xor(tm, 32));
        float mn = fmaxf(m_run, tm);
        float al = __expf(m_run - mn);
        float rs = 0.f;
#pragma unroll
        for (int nt = 0; nt < 8; ++nt)
#pragma unroll
            for (int reg = 0; reg < 4; ++reg) {
                sacc[nt][reg] = __expf(sacc[nt][reg] - mn);
                rs += sacc[nt][reg];
            }
        rs += __shfl_xor(rs, 16);
        rs += __shfl_xor(rs, 32);
        l_run = l_run * al + rs;
        m_run = mn;

        float alr[4];
#pragma unroll
        for (int reg = 0; reg < 4; ++reg) alr[reg] = __shfl(al, quad * 4 + reg);
#pragma unroll
        for (int ntd = 0; ntd < 4; ++ntd)
#pragma unroll
            for (int reg = 0; reg < 4; ++reg) accv[ntd][reg] *= alr[reg];

#pragma unroll
        for (int nt = 0; nt < 8; ++nt) {
            ushort4 pk;
            pk.x = f2h(sacc[nt][0]); pk.y = f2h(sacc[nt][1]);
            pk.z = f2h(sacc[nt][2]); pk.w = f2h(sacc[nt][3]);
            *(ushort4*)&Sp[l16 * 136 + nt * 16 + quad * 4] = pk;
        }

#pragma unroll
        for (int c4 = 0; c4 < 4; ++c4) {
            v8s ap = *(const v8s*)&Sp[l16 * 136 + c4 * 32 + quad * 8];
#pragma unroll
            for (int ntd = 0; ntd < 4; ++ntd) {
                v8s bv8 = *(const v8s*)(Vg + (size_t)(ntd * 16 + l16) * S_LEN +
                                        k0 + c4 * 32 + quad * 8);
                accv[ntd] = __builtin_amdgcn_mfma_f32_16x16x32_f16(ap, bv8, accv[ntd], 0, 0, 0);
            }
        }
    }
#undef ISSUE_POS

    MlAll[wave][lane * 2]     = m_run;
    MlAll[wave][lane * 2 + 1] = l_run;
    if (wave != 0) {
        float* accSlot = (float*)&SpAll[wave][0];
#pragma unroll
        for (int ntd = 0; ntd < 4; ++ntd)
#pragma unroll
            for (int reg = 0; reg < 4; ++reg)
                accSlot[lane * 16 + ntd * 4 + reg] = accv[ntd][reg];
    }
    __syncthreads();
    if (wave == 0) {
        const int bb = g >> 3, h = g & 7;
        float ew[4][4], inv[4];
#pragma unroll
        for (int reg = 0; reg < 4; ++reg) {
            int qi = quad * 4 + reg;
            float mw[4], lw[4];
#pragma unroll
            for (int w = 0; w < 4; ++w) {
                mw[w] = MlAll[w][qi * 2];
                lw[w] = MlAll[w][qi * 2 + 1];
            }
            float ms = fmaxf(fmaxf(mw[0], mw[1]), fmaxf(mw[2], mw[3]));
            float lt = 0.f;
#pragma unroll
            for (int w = 0; w < 4; ++w) {
                ew[reg][w] = __expf(mw[w] - ms);
                lt += lw[w] * ew[reg][w];
            }
            inv[reg] = 1.f / lt;
        }
#pragma unroll
        for (int ntd = 0; ntd < 4; ++ntd) {
#pragma unroll
            for (int reg = 0; reg < 4; ++reg) {
                float o = accv[ntd][reg] * ew[reg][0];
#pragma unroll
                for (int w = 1; w < 4; ++w) {
                    const float* slot = (const float*)&SpAll[w][0];
                    o += slot[lane * 16 + ntd * 4 + reg] * ew[reg][w];
                }
                int qq = q0 + quad * 4 + reg;
                ctx[((size_t)(bb * S_LEN + qq)) * DM + h * DHD + ntd * 16 + l16] =
                    f2h(o * inv[reg]);
            }
        }
    }
}

// ---------------------------------------------------------------------------
// out_mfma: out(fp32)[s][n] = ctx(fp16) @ Wo + bo.  SWAPPED: C[n][s] ->
// float4 stores.  grid (32, 4): x = s-tile(128), y = n-tile(128).
// ---------------------------------------------------------------------------
__global__ __launch_bounds__(256)
void out_mfma(const float* __restrict__ bo, const char* __restrict__ wsb,
              float* __restrict__ out)
{
    const int t = threadIdx.x;
    const int wave = t >> 6, lane = t & 63;
    const int quad = lane >> 4, l16 = lane & 15;
    const int wm = wave >> 1, wn = wave & 1;
    const int n0 = blockIdx.y * 128 + wm * 64;
    const int s0 = blockIdx.x * 128 + wn * 64;
    const unsigned short* A = (const unsigned short*)(wsb + BY_WT) + (size_t)4 * WT_MAT_HALFS;
    const unsigned short* B = (const unsigned short*)(wsb + BY_CTX);

    v4f acc[4][4];
#pragma unroll
    for (int i = 0; i < 4; ++i)
#pragma unroll
        for (int j = 0; j < 4; ++j) acc[i][j] = (v4f){0.f, 0.f, 0.f, 0.f};

    for (int kk = 0; kk < 16; ++kk) {
        v8s af[4], bf[4];
#pragma unroll
        for (int i = 0; i < 4; ++i) {
            af[i] = *(const v8s*)(A + (size_t)(n0 + i * 16 + l16) * 512 + kk * 32 + quad * 8);
            bf[i] = *(const v8s*)(B + (size_t)(s0 + i * 16 + l16) * 512 + kk * 32 + quad * 8);
        }
#pragma unroll
        for (int i = 0; i < 4; ++i)
#pragma unroll
            for (int j = 0; j < 4; ++j)
                acc[i][j] = __builtin_amdgcn_mfma_f32_16x16x32_f16(af[i], bf[j], acc[i][j], 0, 0, 0);
    }

#pragma unroll
    for (int i = 0; i < 4; ++i) {
        int nb = n0 + i * 16 + quad * 4;
        float4 b4 = *(const float4*)(bo + nb);
#pragma unroll
        for (int j = 0; j < 4; ++j) {
            int s = s0 + j * 16 + l16;
            *(float4*)(out + (size_t)s * DM + nb) =
                make_float4(acc[i][j][0] + b4.x, acc[i][j][1] + b4.y,
                            acc[i][j][2] + b4.z, acc[i][j][3] + b4.w);
        }
    }
}

// Fallback when ws_size is insufficient: clean mismatch instead of OOB writes.
__global__ void zero_fill(float* __restrict__ p, int n)
{
    int i = blockIdx.x * 256 + threadIdx.x;
    if (i < n) p[i] = 0.f;
}

// ---------------------------------------------------------------------------
extern "C" void kernel_launch(void* const* d_in, const int* in_sizes, int n_in,
                              void* d_out, int out_size, void* d_ws, size_t ws_size,
                              hipStream_t stream)
{
    const float* x   = (const float*)d_in[0];
    const float* pos = (const float*)d_in[1];
    const float* Wq  = (const float*)d_in[2];
    const float* bq  = (const float*)d_in[3];
    const float* Wk  = (const float*)d_in[4];
    const float* bk  = (const float*)d_in[5];
    const float* Wv  = (const float*)d_in[6];
    const float* bv  = (const float*)d_in[7];
    const float* Wp  = (const float*)d_in[8];
    const float* u   = (const float*)d_in[9];
    const float* v   = (const float*)d_in[10];
    const float* Wo  = (const float*)d_in[11];
    const float* bo  = (const float*)d_in[12];
    char* wsb  = (char*)d_ws;
    float* out = (float*)d_out;

    // Workspace guard: need BY_PP + >=1 head of raw Ppos + DMA slack.
    if (ws_size < (size_t)BY_PP + PP_HEAD_BYTES + 4096) {
        zero_fill<<<(out_size + 255) / 256, 256, 0, stream>>>(out, out_size);
        return;
    }

    // 1. dtype prep
    conv_inputs<<<dim3(2048, 1, 2), 256, 0, stream>>>(x, pos, wsb);
    conv_wt<<<dim3(8, 8, 5), 256, 0, stream>>>(Wq, Wk, Wv, Wp, Wo, wsb);

    // 2. projections (fp16 MFMA)
    proj_mfma<<<dim3(32, 4, 4), 256, 0, stream>>>(bq, bk, bv, u, v, wsb);

    // 3. attention in head-chunks sized to workspace (DMA slack: windows may
    //    overread ~64 B past the last head's Ppos; stays inside d_ws).
    int c = (int)((ws_size - 4096 - (size_t)BY_PP) / (size_t)PP_HEAD_BYTES);
    if (c < 1) c = 1;
    if (c > NBH) c = NBH;

    for (int g0 = 0; g0 < NBH; g0 += c) {
        int cc = (NBH - g0 < c) ? (NBH - g0) : c;
        pos_gemm<<<dim3(16, 16, cc), 256, 0, stream>>>(
            (const unsigned short*)(wsb + BY_QV),
            (const unsigned short*)(wsb + BY_PB),
            (unsigned short*)(wsb + BY_PP), g0);
        attn_fused<<<dim3(cc * 128), 256, 0, stream>>>(
            (const unsigned short*)(wsb + BY_QU),
            (const unsigned short*)(wsb + BY_K),
            (const unsigned short*)(wsb + BY_VT),
            (const unsigned short*)(wsb + BY_PP),
            (unsigned short*)(wsb + BY_CTX), g0);
    }

    // 4. output projection (fp16 MFMA, fp32 out)
    out_mfma<<<dim3(32, 4), 256, 0, stream>>>(bo, wsb, out);
}